// Round 5
// baseline (1332.688 us; speedup 1.0000x reference)
//
#include <hip/hip_runtime.h>

#define KS 1.8033688011112042f  // log2(e)/0.8
#define NTOK 8192
#define VV 8192
#define CHB 51200
#define WS_CC2B 1638400

typedef float f4 __attribute__((ext_vector_type(4)));
typedef short s8v __attribute__((ext_vector_type(8)));
typedef unsigned int u32;
#define AS1 __attribute__((address_space(1)))
#define AS3 __attribute__((address_space(3)))

// RNE float->bf16, bit-ops (prep only — cold)
static __device__ __forceinline__ unsigned short f2bf(float f) {
  u32 u = __float_as_uint(f);
  return (unsigned short)((u + 0x7fffu + ((u >> 16) & 1u)) >> 16);
}
// HW packed conversion: D.lo16 = bf16(a), D.hi16 = bf16(b)
static __device__ __forceinline__ u32 cvtpk(float a, float b) {
  u32 r;
  asm("v_cvt_pk_bf16_f32 %0, %1, %2" : "=v"(r) : "v"(a), "v"(b));
  return r;
}
static __device__ __forceinline__ float lof(u32 h) {  // low bf16 as f32
  return __uint_as_float(h << 16);
}
static __device__ __forceinline__ float hif(u32 h) {  // high bf16 as f32
  return __uint_as_float(h & 0xffff0000u);
}

// ws layout: 32 chunks (256 codes), chunk-major, 51200 B each:
//   [0     ,16384) FragWh : 16 subtiles x 64 lanes x 8 bf16 (A of mfma1, W_hi*KS)
//   [16384 ,32768) FragWl
//   [32768 ,40960) FragCh : 8 PAIRS x 64 lanes x 8 bf16 (A of mfma2, K=32 pairing)
//   [40960 ,49152) FragCl
//   [49152 ,50176) BB fp32[256] (b*KS)   [50176,51200) BT fp32[256] (tp*KS)
// then CC2 fp32[8192]. Total 1671168 B.
// ALL mfma are 16x16x32_bf16 (layout validated by the refcheck'd GEMM ladder).
// mfma1 (logits^T): M=code16, N=tok16, K=32 ([xh;xl]); A repeats W over d=k&15.
// mfma2 (mu^T): M=d16, N=tok16, K=32 over a subtile PAIR (p0=2s, p1=2s+1):
//   k=g*8+j -> code = (j<4 ? p0 : p1)*16 + g*4 + (j&3); B elem j = E[code][tok]
//   which is exactly the e-vector a lane holds from mfma1's D of p0,p1.
__global__ __launch_bounds__(64) void prep_kernel(
    const float* __restrict__ cb, const float* __restrict__ Wm,
    const float* __restrict__ bm, const float* __restrict__ tp,
    char* __restrict__ ws) {
  const int ct = blockIdx.x;  // subtile 0..511 (16 codes)
  const int l = threadIdx.x;
  const int g = l >> 4, q = l & 15;
  const int c = ct >> 4, p = ct & 15;
  const int s = p >> 1, par = p & 1;
  char* chunk = ws + (size_t)c * CHB;
  {  // W fragment (A of mfma1): row=code=ct*16+q, k=g*8+j, d=k&15
    const int code = ct * 16 + q;
    unsigned short wh[8], wl[8];
#pragma unroll
    for (int j = 0; j < 8; j++) {
      int d = (g * 8 + j) & 15;
      float v = Wm[d * VV + code] * KS;
      unsigned short h = f2bf(v);
      wh[j] = h;
      wl[j] = f2bf(v - __uint_as_float((u32)h << 16));
    }
    uint4 hv, lv;
    hv.x = (u32)wh[0] | ((u32)wh[1] << 16); hv.y = (u32)wh[2] | ((u32)wh[3] << 16);
    hv.z = (u32)wh[4] | ((u32)wh[5] << 16); hv.w = (u32)wh[6] | ((u32)wh[7] << 16);
    lv.x = (u32)wl[0] | ((u32)wl[1] << 16); lv.y = (u32)wl[2] | ((u32)wl[3] << 16);
    lv.z = (u32)wl[4] | ((u32)wl[5] << 16); lv.w = (u32)wl[6] | ((u32)wl[7] << 16);
    *(uint4*)(chunk + p * 1024 + l * 16) = hv;
    *(uint4*)(chunk + 16384 + p * 1024 + l * 16) = lv;
  }
  {  // C pair-fragment (A of mfma2): block fills elems par*4+{0..3} of pair s
    unsigned short ch[4], cl_[4];
#pragma unroll
    for (int j = 0; j < 4; j++) {
      int code = ct * 16 + g * 4 + j;
      float v = cb[code * 16 + q];
      unsigned short h = f2bf(v);
      ch[j] = h;
      cl_[j] = f2bf(v - __uint_as_float((u32)h << 16));
    }
    uint2 hv = make_uint2((u32)ch[0] | ((u32)ch[1] << 16),
                          (u32)ch[2] | ((u32)ch[3] << 16));
    uint2 lv = make_uint2((u32)cl_[0] | ((u32)cl_[1] << 16),
                          (u32)cl_[2] | ((u32)cl_[3] << 16));
    *(uint2*)(chunk + 32768 + s * 1024 + l * 16 + par * 8) = hv;
    *(uint2*)(chunk + 40960 + s * 1024 + l * 16 + par * 8) = lv;
  }
  if (l < 16) {
    const int code = ct * 16 + l;
    *(float*)(chunk + 49152 + p * 64 + l * 4) = bm[code] * KS;
    *(float*)(chunk + 50176 + p * 64 + l * 4) = tp[code] * KS;
    float ss = 0.f;
#pragma unroll
    for (int d = 0; d < 16; d++) { float v = cb[code * 16 + d]; ss = fmaf(v, v, ss); }
    *(float*)(ws + WS_CC2B + code * 4) = ss;
  }
}

// 256 blocks x 1024 thr (16 waves = 4 waves/SIMD). R5 redesign: ALL fragments
// (W,C hi/lo for 2 chunks per wave = 384 VGPR/lane) live in REGISTERS for the
// whole kernel, loaded from L2 once. No per-phase staging, no fragment
// ds_reads, barriers 448 -> 28 (2/phase). Biases for all 32 chunks sit in LDS
// statically (64 KB, broadcast reads). Each wave computes BOTH token tiles for
// its 512 codes; partials merged via LDS twice per phase.
// CRITICAL (rule #20): every fragment-array index is compile-time (full unroll).
// Arithmetic identical to R4 (same mfma sequence/packing) -> same absmax.
__global__ __launch_bounds__(1024, 4) void flow_kernel(
    const float* __restrict__ x0, const char* __restrict__ ws,
    const float* __restrict__ cb, const int* __restrict__ nsp,
    float* __restrict__ out) {
  __shared__ __align__(16) char smem[108544];
  char* biasL = smem;                       // [32 chunks][2048 B] BB|BT
  float* xT = (float*)(smem + 65536);       // [32][16] base state
  float* xM = (float*)(smem + 67584);       // [32][16] midpoint state
  char* redMp = smem + 69632;               // [32][64] f4 macc partials (32 KB)
  float* redL = (float*)(smem + 102400);    // [16][32] lsum partials
  float* redV = (float*)(smem + 104448);    // [16][32] VQ min val
  int* redI = (int*)(smem + 106496);        // [16][32] VQ min idx
  const float* CC2 = (const float*)(ws + WS_CC2B);

  const int tid = threadIdx.x;
  const int lane = tid & 63, wave = tid >> 6;  // 16 waves; wave owns chunks 2w,2w+1
  const int g = lane >> 4, q = lane & 15;
  const int tok0 = blockIdx.x * 32;

  if (tid < 128)
    *(float4*)(xT + tid * 4) = *(const float4*)(x0 + tok0 * 16 + tid * 4);
  // biases -> LDS once (wave-uniform dst base + lane*16: valid global_load_lds)
#pragma unroll
  for (int sw = 0; sw < 4; sw++) {
    const int c = sw * 8 + (tid >> 7);
    const int off = (tid & 127) * 16;
    __builtin_amdgcn_global_load_lds(
        (const AS1 u32*)(ws + (size_t)c * CHB + 49152 + off),
        (AS3 u32*)(biasL + c * 2048 + off), 16, 0, 0);
  }
  // fragments -> registers (one-time, L2-resident after prep)
  s8v Wh[2][16], Wl[2][16], Cfh[2][8], Cfl[2][8];
#pragma unroll
  for (int cc = 0; cc < 2; cc++) {
    const char* chs = ws + (size_t)(wave * 2 + cc) * CHB;
#pragma unroll
    for (int p = 0; p < 16; p++) {
      Wh[cc][p] = *(const s8v*)(chs + p * 1024 + lane * 16);
      Wl[cc][p] = *(const s8v*)(chs + 16384 + p * 1024 + lane * 16);
    }
#pragma unroll
    for (int sp = 0; sp < 8; sp++) {
      Cfh[cc][sp] = *(const s8v*)(chs + 32768 + sp * 1024 + lane * 16);
      Cfl[cc][sp] = *(const s8v*)(chs + 40960 + sp * 1024 + lane * 16);
    }
  }
  __syncthreads();

  const int n_steps = *nsp;
  const float dt = 1.0f / (float)(n_steps - 1);

  for (int step = 0; step < n_steps - 1; step++) {
#pragma unroll 1
    for (int mh = 0; mh < 2; mh++) {
      const float tt = (float)step * dt + (mh ? 0.5f * dt : 0.0f);
      const float* xsrc = mh ? xM : xT;
      // B-frags of mfma1 for both tiles: col=tok=q, k=g*8+j;
      // k<16 -> xh[d=k], k>=16 -> xl[d=k-16]. Group g covers d=(g&1)*8..+7.
      union { u32 u[4]; s8v s; } Bx0, Bx1;
#pragma unroll
      for (int T = 0; T < 2; T++) {
        const float* xp = xsrc + (T * 16 + q) * 16 + (g & 1) * 8;
        float4 a = *(const float4*)(xp);
        float4 b = *(const float4*)(xp + 4);
        u32 h0 = cvtpk(a.x, a.y), h1 = cvtpk(a.z, a.w);
        u32 h2 = cvtpk(b.x, b.y), h3 = cvtpk(b.z, b.w);
        u32 r0, r1, r2, r3;
        if (g < 2) {
          r0 = h0; r1 = h1; r2 = h2; r3 = h3;
        } else {
          r0 = cvtpk(a.x - lof(h0), a.y - hif(h0));
          r1 = cvtpk(a.z - lof(h1), a.w - hif(h1));
          r2 = cvtpk(b.x - lof(h2), b.y - hif(h2));
          r3 = cvtpk(b.z - lof(h3), b.w - hif(h3));
        }
        if (T == 0) { Bx0.u[0] = r0; Bx0.u[1] = r1; Bx0.u[2] = r2; Bx0.u[3] = r3; }
        else        { Bx1.u[0] = r0; Bx1.u[1] = r1; Bx1.u[2] = r2; Bx1.u[3] = r3; }
      }
      f4 macc0 = {0.f, 0.f, 0.f, 0.f}, macc1 = {0.f, 0.f, 0.f, 0.f};
      float ls0 = 0.f, ls1 = 0.f;

      auto TBODY = [&](const s8v& BX, f4& MACC, float& LS, const s8v& Ah0,
                       const s8v& Al0, const s8v& Ah1, const s8v& Al1,
                       const s8v& Chf, const s8v& Clf, const float4& z0,
                       const float4& z1) {
        f4 D0 = {0.f, 0.f, 0.f, 0.f};
        D0 = __builtin_amdgcn_mfma_f32_16x16x32_bf16(Ah0, BX, D0, 0, 0, 0);
        D0 = __builtin_amdgcn_mfma_f32_16x16x32_bf16(Al0, BX, D0, 0, 0, 0);
        f4 D1 = {0.f, 0.f, 0.f, 0.f};
        D1 = __builtin_amdgcn_mfma_f32_16x16x32_bf16(Ah1, BX, D1, 0, 0, 0);
        D1 = __builtin_amdgcn_mfma_f32_16x16x32_bf16(Al1, BX, D1, 0, 0, 0);
        float e0 = exp2f(fminf(D0[0] + z0.x, 125.f));
        float e1 = exp2f(fminf(D0[1] + z0.y, 125.f));
        float e2 = exp2f(fminf(D0[2] + z0.z, 125.f));
        float e3 = exp2f(fminf(D0[3] + z0.w, 125.f));
        float e4 = exp2f(fminf(D1[0] + z1.x, 125.f));
        float e5 = exp2f(fminf(D1[1] + z1.y, 125.f));
        float e6 = exp2f(fminf(D1[2] + z1.z, 125.f));
        float e7 = exp2f(fminf(D1[3] + z1.w, 125.f));
        LS += ((e0 + e1) + (e2 + e3)) + ((e4 + e5) + (e6 + e7));
        union { u32 u[4]; s8v s; } Eh, El;
        Eh.u[0] = cvtpk(e0, e1); Eh.u[1] = cvtpk(e2, e3);
        Eh.u[2] = cvtpk(e4, e5); Eh.u[3] = cvtpk(e6, e7);
        El.u[0] = cvtpk(e0 - lof(Eh.u[0]), e1 - hif(Eh.u[0]));
        El.u[1] = cvtpk(e2 - lof(Eh.u[1]), e3 - hif(Eh.u[1]));
        El.u[2] = cvtpk(e4 - lof(Eh.u[2]), e5 - hif(Eh.u[2]));
        El.u[3] = cvtpk(e6 - lof(Eh.u[3]), e7 - hif(Eh.u[3]));
        MACC = __builtin_amdgcn_mfma_f32_16x16x32_bf16(Chf, Eh.s, MACC, 0, 0, 0);
        MACC = __builtin_amdgcn_mfma_f32_16x16x32_bf16(Chf, El.s, MACC, 0, 0, 0);
        MACC = __builtin_amdgcn_mfma_f32_16x16x32_bf16(Clf, Eh.s, MACC, 0, 0, 0);
      };

#pragma unroll
      for (int cc = 0; cc < 2; cc++) {
        const char* bias = biasL + (wave * 2 + cc) * 2048;
#pragma unroll
        for (int sp = 0; sp < 8; sp++) {
          float4 bb0 = *(const float4*)(bias + (2 * sp) * 64 + g * 16);
          float4 bt0 = *(const float4*)(bias + 1024 + (2 * sp) * 64 + g * 16);
          float4 bb1 = *(const float4*)(bias + (2 * sp + 1) * 64 + g * 16);
          float4 bt1 = *(const float4*)(bias + 1024 + (2 * sp + 1) * 64 + g * 16);
          float4 z0, z1;  // bias folded with tt (tile-independent)
          z0.x = fmaf(tt, bt0.x, bb0.x); z0.y = fmaf(tt, bt0.y, bb0.y);
          z0.z = fmaf(tt, bt0.z, bb0.z); z0.w = fmaf(tt, bt0.w, bb0.w);
          z1.x = fmaf(tt, bt1.x, bb1.x); z1.y = fmaf(tt, bt1.y, bb1.y);
          z1.z = fmaf(tt, bt1.z, bb1.z); z1.w = fmaf(tt, bt1.w, bb1.w);
          TBODY(Bx0.s, macc0, ls0, Wh[cc][2 * sp], Wl[cc][2 * sp],
                Wh[cc][2 * sp + 1], Wl[cc][2 * sp + 1], Cfh[cc][sp], Cfl[cc][sp],
                z0, z1);
          TBODY(Bx1.s, macc1, ls1, Wh[cc][2 * sp], Wl[cc][2 * sp],
                Wh[cc][2 * sp + 1], Wl[cc][2 * sp + 1], Cfh[cc][sp], Cfl[cc][sp],
                z0, z1);
        }
      }
      // partial exchange: lsum reduced over g (lanes q,q+16,q+32,q+48)
      ls0 += __shfl_xor(ls0, 16, 64); ls0 += __shfl_xor(ls0, 32, 64);
      ls1 += __shfl_xor(ls1, 16, 64); ls1 += __shfl_xor(ls1, 32, 64);
      *(f4*)(redMp + ((wave * 2 + 0) * 64 + lane) * 16) = macc0;
      *(f4*)(redMp + ((wave * 2 + 1) * 64 + lane) * 16) = macc1;
      if (lane < 16) {
        redL[wave * 32 + lane] = ls0;
        redL[wave * 32 + 16 + lane] = ls1;
      }
      __syncthreads();
      if ((wave & 7) == 0) {  // waves 0 (tile0) and 8 (tile1) finalize
        const int T2 = wave >> 3;
        f4 m = {0.f, 0.f, 0.f, 0.f};
        float l2 = 0.f;
#pragma unroll
        for (int w = 0; w < 16; w++) {
          f4 o = *(const f4*)(redMp + ((w * 2 + T2) * 64 + lane) * 16);
          m += o;
          l2 += redL[w * 32 + T2 * 16 + q];
        }
        const float inv = 1.0f / fmaxf(l2, 1e-37f);
        const float inv1 = 1.0f / (1.0f - tt + 1e-10f);
        const float cf = (mh == 0) ? (0.5f * dt * inv1) : (dt * inv1);
        // lane owns (tok=q, d=g*4+j) of its tile: contiguous float4
        float4 xb = *(const float4*)(xT + (T2 * 16 + q) * 16 + g * 4);
        float4 xs = mh ? *(const float4*)(xM + (T2 * 16 + q) * 16 + g * 4) : xb;
        float4 xn;
        xn.x = fmaf(cf, m[0] * inv - xs.x, xb.x);
        xn.y = fmaf(cf, m[1] * inv - xs.y, xb.y);
        xn.z = fmaf(cf, m[2] * inv - xs.z, xb.z);
        xn.w = fmaf(cf, m[3] * inv - xs.w, xb.w);
        *(float4*)((mh ? xT : xM) + (T2 * 16 + q) * 16 + g * 4) = xn;
      }
      __syncthreads();
    }
  }

  // ---- outputs: x_final ----
  if (tid < 128)
    *(float4*)(out + tok0 * 16 + tid * 4) = *(const float4*)(xT + tid * 4);

  // ---- VQ argmin: d = ||c||^2 - 2 x.c; wave sweeps its 512 codes for all
  // 32 tokens (4 at a time, fully unrolled: no runtime-indexed arrays). ----
  const int wbase = wave * 512;
#pragma unroll 1
  for (int tg = 0; tg < 8; tg++) {
    float xr[4][16];
#pragma unroll
    for (int t = 0; t < 4; t++)
#pragma unroll
      for (int d4 = 0; d4 < 4; d4++)
        *(float4*)(&xr[t][d4 * 4]) = *(const float4*)(xT + (tg * 4 + t) * 16 + d4 * 4);
    float mv[4] = {3.402823466e38f, 3.402823466e38f, 3.402823466e38f, 3.402823466e38f};
    int mi[4] = {0, 0, 0, 0};
#pragma unroll 1
    for (int i = 0; i < 8; i++) {
      const int code = wbase + i * 64 + lane;
      float cr[16];
#pragma unroll
      for (int d4 = 0; d4 < 4; d4++)
        *(float4*)(&cr[d4 * 4]) = *(const float4*)(cb + code * 16 + d4 * 4);
      const float cc = CC2[code];
#pragma unroll
      for (int t = 0; t < 4; t++) {
        float dot = 0.f;
#pragma unroll
        for (int d = 0; d < 16; d++) dot = fmaf(xr[t][d], cr[d], dot);
        float dist = fmaf(-2.f, dot, cc);
        if (dist < mv[t]) { mv[t] = dist; mi[t] = code; }
      }
    }
#pragma unroll
    for (int t = 0; t < 4; t++) {
#pragma unroll
      for (int m = 1; m < 64; m <<= 1) {
        float ov = __shfl_xor(mv[t], m, 64);
        int oi = __shfl_xor(mi[t], m, 64);
        if (ov < mv[t] || (ov == mv[t] && oi < mi[t])) { mv[t] = ov; mi[t] = oi; }
      }
      if (lane == 0) {
        redV[wave * 32 + tg * 4 + t] = mv[t];
        redI[wave * 32 + tg * 4 + t] = mi[t];
      }
    }
  }
  __syncthreads();
  if (tid < 32) {
    float bv = redV[tid];
    int bi = redI[tid];
#pragma unroll
    for (int w = 1; w < 16; w++) {
      float ov = redV[w * 32 + tid];
      int oi = redI[w * 32 + tid];
      if (ov < bv || (ov == bv && oi < bi)) { bv = ov; bi = oi; }
    }
    out[NTOK * 16 + tok0 + tid] = (float)bi;
  }
}

extern "C" void kernel_launch(void* const* d_in, const int* in_sizes, int n_in,
                              void* d_out, int out_size, void* d_ws, size_t ws_size,
                              hipStream_t stream) {
  const float* x0 = (const float*)d_in[0];
  const float* cb = (const float*)d_in[1];
  const float* Wm = (const float*)d_in[2];
  const float* bm = (const float*)d_in[3];
  const float* tp = (const float*)d_in[4];
  const int* ns = (const int*)d_in[5];
  char* ws = (char*)d_ws;  // needs 1671168 B
  float* out = (float*)d_out;

  prep_kernel<<<512, 64, 0, stream>>>(cb, Wm, bm, tp, ws);
  flow_kernel<<<256, 1024, 0, stream>>>(x0, ws, cb, ns, out);
}

// Round 6
// 535.723 us; speedup vs baseline: 2.4876x; 2.4876x over previous
//
#include <hip/hip_runtime.h>

#define KS 1.8033688011112042f  // log2(e)/0.8
#define NTOK 8192
#define VV 8192
#define CHB 51200
#define WS_CC2B 1638400

typedef float f4 __attribute__((ext_vector_type(4)));
typedef short s8v __attribute__((ext_vector_type(8)));
typedef unsigned int u32;
#define AS1 __attribute__((address_space(1)))
#define AS3 __attribute__((address_space(3)))

// RNE float->bf16, bit-ops (prep only — cold)
static __device__ __forceinline__ unsigned short f2bf(float f) {
  u32 u = __float_as_uint(f);
  return (unsigned short)((u + 0x7fffu + ((u >> 16) & 1u)) >> 16);
}
// HW packed conversion: D.lo16 = bf16(a), D.hi16 = bf16(b)
static __device__ __forceinline__ u32 cvtpk(float a, float b) {
  u32 r;
  asm("v_cvt_pk_bf16_f32 %0, %1, %2" : "=v"(r) : "v"(a), "v"(b));
  return r;
}
static __device__ __forceinline__ float lof(u32 h) {  // low bf16 as f32
  return __uint_as_float(h << 16);
}
static __device__ __forceinline__ float hif(u32 h) {  // high bf16 as f32
  return __uint_as_float(h & 0xffff0000u);
}

// ws layout: 32 chunks (256 codes), chunk-major, 51200 B each:
//   [0     ,16384) FragWh : 16 subtiles x 64 lanes x 8 bf16 (A of mfma1, W_hi*KS)
//   [16384 ,32768) FragWl
//   [32768 ,40960) FragCh : 8 PAIRS x 64 lanes x 8 bf16 (A of mfma2, K=32 pairing)
//   [40960 ,49152) FragCl
//   [49152 ,50176) BB fp32[256] (b*KS)   [50176,51200) BT fp32[256] (tp*KS)
// then CC2 fp32[8192]. Total 1671168 B.
// ALL mfma are 16x16x32_bf16 (layout validated by the refcheck'd GEMM ladder).
// mfma1 (logits^T): M=code16, N=tok16, K=32 ([xh;xl]); A repeats W over d=k&15.
// mfma2 (mu^T): M=d16, N=tok16, K=32 over a subtile PAIR (p0=2s, p1=2s+1):
//   k=g*8+j -> code = (j<4 ? p0 : p1)*16 + g*4 + (j&3); B elem j = E[code][tok]
//   which is exactly the e-vector a lane holds from mfma1's D of p0,p1.
__global__ __launch_bounds__(64) void prep_kernel(
    const float* __restrict__ cb, const float* __restrict__ Wm,
    const float* __restrict__ bm, const float* __restrict__ tp,
    char* __restrict__ ws) {
  const int ct = blockIdx.x;  // subtile 0..511 (16 codes)
  const int l = threadIdx.x;
  const int g = l >> 4, q = l & 15;
  const int c = ct >> 4, p = ct & 15;
  const int s = p >> 1, par = p & 1;
  char* chunk = ws + (size_t)c * CHB;
  {  // W fragment (A of mfma1): row=code=ct*16+q, k=g*8+j, d=k&15
    const int code = ct * 16 + q;
    unsigned short wh[8], wl[8];
#pragma unroll
    for (int j = 0; j < 8; j++) {
      int d = (g * 8 + j) & 15;
      float v = Wm[d * VV + code] * KS;
      unsigned short h = f2bf(v);
      wh[j] = h;
      wl[j] = f2bf(v - __uint_as_float((u32)h << 16));
    }
    uint4 hv, lv;
    hv.x = (u32)wh[0] | ((u32)wh[1] << 16); hv.y = (u32)wh[2] | ((u32)wh[3] << 16);
    hv.z = (u32)wh[4] | ((u32)wh[5] << 16); hv.w = (u32)wh[6] | ((u32)wh[7] << 16);
    lv.x = (u32)wl[0] | ((u32)wl[1] << 16); lv.y = (u32)wl[2] | ((u32)wl[3] << 16);
    lv.z = (u32)wl[4] | ((u32)wl[5] << 16); lv.w = (u32)wl[6] | ((u32)wl[7] << 16);
    *(uint4*)(chunk + p * 1024 + l * 16) = hv;
    *(uint4*)(chunk + 16384 + p * 1024 + l * 16) = lv;
  }
  {  // C pair-fragment (A of mfma2): block fills elems par*4+{0..3} of pair s
    unsigned short ch[4], cl_[4];
#pragma unroll
    for (int j = 0; j < 4; j++) {
      int code = ct * 16 + g * 4 + j;
      float v = cb[code * 16 + q];
      unsigned short h = f2bf(v);
      ch[j] = h;
      cl_[j] = f2bf(v - __uint_as_float((u32)h << 16));
    }
    uint2 hv = make_uint2((u32)ch[0] | ((u32)ch[1] << 16),
                          (u32)ch[2] | ((u32)ch[3] << 16));
    uint2 lv = make_uint2((u32)cl_[0] | ((u32)cl_[1] << 16),
                          (u32)cl_[2] | ((u32)cl_[3] << 16));
    *(uint2*)(chunk + 32768 + s * 1024 + l * 16 + par * 8) = hv;
    *(uint2*)(chunk + 40960 + s * 1024 + l * 16 + par * 8) = lv;
  }
  if (l < 16) {
    const int code = ct * 16 + l;
    *(float*)(chunk + 49152 + p * 64 + l * 4) = bm[code] * KS;
    *(float*)(chunk + 50176 + p * 64 + l * 4) = tp[code] * KS;
    float ss = 0.f;
#pragma unroll
    for (int d = 0; d < 16; d++) { float v = cb[code * 16 + d]; ss = fmaf(v, v, ss); }
    *(float*)(ws + WS_CC2B + code * 4) = ss;
  }
}

// R6: direct L2->VGPR fragment streaming. 256 blocks x 1024 thr (16 waves =
// 4 waves/SIMD). Wave (par=w>>3, s=w&7) computes BOTH token tiles for pair s
// over chunks {par, par+2, ..., par+30}: fragment set read exactly ONCE per
// CU per phase, NO LDS staging, NO chunk-loop barriers (fragments are
// wave-private; compiler vmcnt self-syncs). Named double-buffered register
// set (2 x 6 s8v = 48 VGPR), software-pipelined one chunk ahead. Biases for
// all 32 chunks static in LDS (64 KB, broadcast reads). Barriers: 2/phase.
// CRITICAL (rule #20, R5 lesson): NO register arrays — named scalars only;
// per-wave VGPR budget is 128 at 4 waves/SIMD.
// Arithmetic identical to R4 (same mfma sequence/packing) -> same absmax.
__global__ __launch_bounds__(1024, 4) void flow_kernel(
    const float* __restrict__ x0, const char* __restrict__ ws,
    const float* __restrict__ cb, const int* __restrict__ nsp,
    float* __restrict__ out) {
  __shared__ __align__(16) char smem[108544];
  char* biasL = smem;                       // [32 chunks][2048 B] BB|BT
  float* xT = (float*)(smem + 65536);       // [32][16] base state
  float* xM = (float*)(smem + 67584);       // [32][16] midpoint state
  char* redMp = smem + 69632;               // [16 waves][2 tiles][64] f4 (32 KB)
  float* redL = (float*)(smem + 102400);    // [16][32] lsum partials
  float* redV = (float*)(smem + 104448);    // [16][32] VQ min val
  int* redI = (int*)(smem + 106496);        // [16][32] VQ min idx
  const float* CC2 = (const float*)(ws + WS_CC2B);

  const int tid = threadIdx.x;
  const int lane = tid & 63, wave = tid >> 6;  // 16 waves
  const int s = wave & 7, cpar = wave >> 3;    // pair id, chunk parity
  const int s2 = s * 2;
  const int g = lane >> 4, q = lane & 15;
  const int tok0 = blockIdx.x * 32;

  if (tid < 128)
    *(float4*)(xT + tid * 4) = *(const float4*)(x0 + tok0 * 16 + tid * 4);
  // biases -> LDS once (wave-uniform dst base + lane*16: valid global_load_lds)
#pragma unroll
  for (int sw = 0; sw < 4; sw++) {
    const int c = sw * 8 + (tid >> 7);
    const int off = (tid & 127) * 16;
    __builtin_amdgcn_global_load_lds(
        (const AS1 u32*)(ws + (size_t)c * CHB + 49152 + off),
        (AS3 u32*)(biasL + c * 2048 + off), 16, 0, 0);
  }
  __syncthreads();

  const int n_steps = *nsp;
  const float dt = 1.0f / (float)(n_steps - 1);

  // named double-buffered fragment registers (NO arrays — rule #20)
  s8v aAh0, aAl0, aAh1, aAl1, aCh, aCl;
  s8v bAh0, bAl0, bAh1, bAl1, bCh, bCl;

#define LOADF(P, c) {                                                       \
    const char* _p = ws + (size_t)(c) * CHB;                                \
    P##Ah0 = *(const s8v*)(_p + s2 * 1024 + lane * 16);                     \
    P##Al0 = *(const s8v*)(_p + 16384 + s2 * 1024 + lane * 16);             \
    P##Ah1 = *(const s8v*)(_p + (s2 + 1) * 1024 + lane * 16);               \
    P##Al1 = *(const s8v*)(_p + 16384 + (s2 + 1) * 1024 + lane * 16);       \
    P##Ch = *(const s8v*)(_p + 32768 + s * 1024 + lane * 16);               \
    P##Cl = *(const s8v*)(_p + 40960 + s * 1024 + lane * 16);               \
  }

#define TBODY(AH0, AL0, AH1, AL1, CHF, CLF, BX, MACC, LS, Z0, Z1) {         \
    f4 _D0 = {0.f, 0.f, 0.f, 0.f};                                          \
    _D0 = __builtin_amdgcn_mfma_f32_16x16x32_bf16(AH0, BX, _D0, 0, 0, 0);   \
    _D0 = __builtin_amdgcn_mfma_f32_16x16x32_bf16(AL0, BX, _D0, 0, 0, 0);   \
    f4 _D1 = {0.f, 0.f, 0.f, 0.f};                                          \
    _D1 = __builtin_amdgcn_mfma_f32_16x16x32_bf16(AH1, BX, _D1, 0, 0, 0);   \
    _D1 = __builtin_amdgcn_mfma_f32_16x16x32_bf16(AL1, BX, _D1, 0, 0, 0);   \
    float _e0 = exp2f(fminf(_D0[0] + Z0.x, 125.f));                         \
    float _e1 = exp2f(fminf(_D0[1] + Z0.y, 125.f));                         \
    float _e2 = exp2f(fminf(_D0[2] + Z0.z, 125.f));                         \
    float _e3 = exp2f(fminf(_D0[3] + Z0.w, 125.f));                         \
    float _e4 = exp2f(fminf(_D1[0] + Z1.x, 125.f));                         \
    float _e5 = exp2f(fminf(_D1[1] + Z1.y, 125.f));                         \
    float _e6 = exp2f(fminf(_D1[2] + Z1.z, 125.f));                         \
    float _e7 = exp2f(fminf(_D1[3] + Z1.w, 125.f));                         \
    LS += ((_e0 + _e1) + (_e2 + _e3)) + ((_e4 + _e5) + (_e6 + _e7));        \
    union { u32 u[4]; s8v v; } _Eh, _El;                                    \
    _Eh.u[0] = cvtpk(_e0, _e1); _Eh.u[1] = cvtpk(_e2, _e3);                 \
    _Eh.u[2] = cvtpk(_e4, _e5); _Eh.u[3] = cvtpk(_e6, _e7);                 \
    _El.u[0] = cvtpk(_e0 - lof(_Eh.u[0]), _e1 - hif(_Eh.u[0]));             \
    _El.u[1] = cvtpk(_e2 - lof(_Eh.u[1]), _e3 - hif(_Eh.u[1]));             \
    _El.u[2] = cvtpk(_e4 - lof(_Eh.u[2]), _e5 - hif(_Eh.u[2]));             \
    _El.u[3] = cvtpk(_e6 - lof(_Eh.u[3]), _e7 - hif(_Eh.u[3]));             \
    MACC = __builtin_amdgcn_mfma_f32_16x16x32_bf16(CHF, _Eh.v, MACC, 0, 0, 0); \
    MACC = __builtin_amdgcn_mfma_f32_16x16x32_bf16(CHF, _El.v, MACC, 0, 0, 0); \
    MACC = __builtin_amdgcn_mfma_f32_16x16x32_bf16(CLF, _Eh.v, MACC, 0, 0, 0); \
  }

#define COMPUTE(P, c) {                                                     \
    const char* _bias = biasL + (c) * 2048;                                 \
    float4 _bb0 = *(const float4*)(_bias + s2 * 64 + g * 16);               \
    float4 _bt0 = *(const float4*)(_bias + 1024 + s2 * 64 + g * 16);        \
    float4 _bb1 = *(const float4*)(_bias + (s2 + 1) * 64 + g * 16);         \
    float4 _bt1 = *(const float4*)(_bias + 1024 + (s2 + 1) * 64 + g * 16);  \
    float4 _z0, _z1;                                                        \
    _z0.x = fmaf(tt, _bt0.x, _bb0.x); _z0.y = fmaf(tt, _bt0.y, _bb0.y);     \
    _z0.z = fmaf(tt, _bt0.z, _bb0.z); _z0.w = fmaf(tt, _bt0.w, _bb0.w);     \
    _z1.x = fmaf(tt, _bt1.x, _bb1.x); _z1.y = fmaf(tt, _bt1.y, _bb1.y);     \
    _z1.z = fmaf(tt, _bt1.z, _bb1.z); _z1.w = fmaf(tt, _bt1.w, _bb1.w);     \
    TBODY(P##Ah0, P##Al0, P##Ah1, P##Al1, P##Ch, P##Cl, Bx0.v, macc0, ls0,  \
          _z0, _z1);                                                        \
    TBODY(P##Ah0, P##Al0, P##Ah1, P##Al1, P##Ch, P##Cl, Bx1.v, macc1, ls1,  \
          _z0, _z1);                                                        \
  }

  for (int step = 0; step < n_steps - 1; step++) {
#pragma unroll 1
    for (int mh = 0; mh < 2; mh++) {
      const float tt = (float)step * dt + (mh ? 0.5f * dt : 0.0f);
      const float* xsrc = mh ? xM : xT;
      // B-frags of mfma1 for both tiles: col=tok=q, k=g*8+j;
      // k<16 -> xh[d=k], k>=16 -> xl[d=k-16]. Group g covers d=(g&1)*8..+7.
      union { u32 u[4]; s8v v; } Bx0, Bx1;
#pragma unroll
      for (int T = 0; T < 2; T++) {
        const float* xp = xsrc + (T * 16 + q) * 16 + (g & 1) * 8;
        float4 a = *(const float4*)(xp);
        float4 b = *(const float4*)(xp + 4);
        u32 h0 = cvtpk(a.x, a.y), h1 = cvtpk(a.z, a.w);
        u32 h2 = cvtpk(b.x, b.y), h3 = cvtpk(b.z, b.w);
        u32 r0, r1, r2, r3;
        if (g < 2) {
          r0 = h0; r1 = h1; r2 = h2; r3 = h3;
        } else {
          r0 = cvtpk(a.x - lof(h0), a.y - hif(h0));
          r1 = cvtpk(a.z - lof(h1), a.w - hif(h1));
          r2 = cvtpk(b.x - lof(h2), b.y - hif(h2));
          r3 = cvtpk(b.z - lof(h3), b.w - hif(h3));
        }
        if (T == 0) { Bx0.u[0] = r0; Bx0.u[1] = r1; Bx0.u[2] = r2; Bx0.u[3] = r3; }
        else        { Bx1.u[0] = r0; Bx1.u[1] = r1; Bx1.u[2] = r2; Bx1.u[3] = r3; }
      }
      f4 macc0 = {0.f, 0.f, 0.f, 0.f}, macc1 = {0.f, 0.f, 0.f, 0.f};
      float ls0 = 0.f, ls1 = 0.f;

      // chunk pipeline: this wave's 16 chunks {cpar, cpar+2, ...}, 1 ahead
      LOADF(a, cpar);
#pragma unroll 1
      for (int j = 0; j < 16; j += 2) {
        LOADF(b, cpar + 2 * (j + 1));
        COMPUTE(a, cpar + 2 * j);
        if (j + 2 < 16) LOADF(a, cpar + 2 * (j + 2));
        COMPUTE(b, cpar + 2 * (j + 1));
      }

      // partial exchange: lsum reduced over g (lanes q,q+16,q+32,q+48)
      ls0 += __shfl_xor(ls0, 16, 64); ls0 += __shfl_xor(ls0, 32, 64);
      ls1 += __shfl_xor(ls1, 16, 64); ls1 += __shfl_xor(ls1, 32, 64);
      *(f4*)(redMp + ((wave * 2 + 0) * 64 + lane) * 16) = macc0;
      *(f4*)(redMp + ((wave * 2 + 1) * 64 + lane) * 16) = macc1;
      if (lane < 16) {
        redL[wave * 32 + lane] = ls0;
        redL[wave * 32 + 16 + lane] = ls1;
      }
      __syncthreads();
      if ((wave & 7) == 0) {  // waves 0 (tile0) and 8 (tile1) finalize
        const int T2 = wave >> 3;
        f4 m = {0.f, 0.f, 0.f, 0.f};
        float l2 = 0.f;
#pragma unroll
        for (int w = 0; w < 16; w++) {
          f4 o = *(const f4*)(redMp + ((w * 2 + T2) * 64 + lane) * 16);
          m += o;
          l2 += redL[w * 32 + T2 * 16 + q];
        }
        const float inv = 1.0f / fmaxf(l2, 1e-37f);
        const float inv1 = 1.0f / (1.0f - tt + 1e-10f);
        const float cf = (mh == 0) ? (0.5f * dt * inv1) : (dt * inv1);
        // lane owns (tok=q, d=g*4+j) of its tile: contiguous float4
        float4 xb = *(const float4*)(xT + (T2 * 16 + q) * 16 + g * 4);
        float4 xs = mh ? *(const float4*)(xM + (T2 * 16 + q) * 16 + g * 4) : xb;
        float4 xn;
        xn.x = fmaf(cf, m[0] * inv - xs.x, xb.x);
        xn.y = fmaf(cf, m[1] * inv - xs.y, xb.y);
        xn.z = fmaf(cf, m[2] * inv - xs.z, xb.z);
        xn.w = fmaf(cf, m[3] * inv - xs.w, xb.w);
        *(float4*)((mh ? xT : xM) + (T2 * 16 + q) * 16 + g * 4) = xn;
      }
      __syncthreads();
    }
  }

  // ---- outputs: x_final ----
  if (tid < 128)
    *(float4*)(out + tok0 * 16 + tid * 4) = *(const float4*)(xT + tid * 4);

  // ---- VQ argmin: d = ||c||^2 - 2 x.c; wave sweeps its 512 codes for all
  // 32 tokens (4 at a time, fully unrolled: no runtime-indexed arrays). ----
  const int wbase = wave * 512;
#pragma unroll 1
  for (int tg = 0; tg < 8; tg++) {
    float xr[4][16];
#pragma unroll
    for (int t = 0; t < 4; t++)
#pragma unroll
      for (int d4 = 0; d4 < 4; d4++)
        *(float4*)(&xr[t][d4 * 4]) = *(const float4*)(xT + (tg * 4 + t) * 16 + d4 * 4);
    float mv[4] = {3.402823466e38f, 3.402823466e38f, 3.402823466e38f, 3.402823466e38f};
    int mi[4] = {0, 0, 0, 0};
#pragma unroll 1
    for (int i = 0; i < 8; i++) {
      const int code = wbase + i * 64 + lane;
      float cr[16];
#pragma unroll
      for (int d4 = 0; d4 < 4; d4++)
        *(float4*)(&cr[d4 * 4]) = *(const float4*)(cb + code * 16 + d4 * 4);
      const float cc = CC2[code];
#pragma unroll
      for (int t = 0; t < 4; t++) {
        float dot = 0.f;
#pragma unroll
        for (int d = 0; d < 16; d++) dot = fmaf(xr[t][d], cr[d], dot);
        float dist = fmaf(-2.f, dot, cc);
        if (dist < mv[t]) { mv[t] = dist; mi[t] = code; }
      }
    }
#pragma unroll
    for (int t = 0; t < 4; t++) {
#pragma unroll
      for (int m = 1; m < 64; m <<= 1) {
        float ov = __shfl_xor(mv[t], m, 64);
        int oi = __shfl_xor(mi[t], m, 64);
        if (ov < mv[t] || (ov == mv[t] && oi < mi[t])) { mv[t] = ov; mi[t] = oi; }
      }
      if (lane == 0) {
        redV[wave * 32 + tg * 4 + t] = mv[t];
        redI[wave * 32 + tg * 4 + t] = mi[t];
      }
    }
  }
  __syncthreads();
  if (tid < 32) {
    float bv = redV[tid];
    int bi = redI[tid];
#pragma unroll
    for (int w = 1; w < 16; w++) {
      float ov = redV[w * 32 + tid];
      int oi = redI[w * 32 + tid];
      if (ov < bv || (ov == bv && oi < bi)) { bv = ov; bi = oi; }
    }
    out[NTOK * 16 + tok0 + tid] = (float)bi;
  }
}

extern "C" void kernel_launch(void* const* d_in, const int* in_sizes, int n_in,
                              void* d_out, int out_size, void* d_ws, size_t ws_size,
                              hipStream_t stream) {
  const float* x0 = (const float*)d_in[0];
  const float* cb = (const float*)d_in[1];
  const float* Wm = (const float*)d_in[2];
  const float* bm = (const float*)d_in[3];
  const float* tp = (const float*)d_in[4];
  const int* ns = (const int*)d_in[5];
  char* ws = (char*)d_ws;  // needs 1671168 B
  float* out = (float*)d_out;

  prep_kernel<<<512, 64, 0, stream>>>(cb, Wm, bm, tp, ws);
  flow_kernel<<<256, 1024, 0, stream>>>(x0, ws, cb, ns, out);
}

// Round 7
// 435.417 us; speedup vs baseline: 3.0607x; 1.2304x over previous
//
#include <hip/hip_runtime.h>

#define KS 1.8033688011112042f  // log2(e)/0.8
#define NTOK 8192
#define VV 8192
#define CHB 51200
#define WS_CC2B 1638400

typedef float f4 __attribute__((ext_vector_type(4)));
typedef short s8v __attribute__((ext_vector_type(8)));
typedef unsigned int u32;
#define AS1 __attribute__((address_space(1)))
#define AS3 __attribute__((address_space(3)))

// RNE float->bf16, bit-ops (prep only — cold)
static __device__ __forceinline__ unsigned short f2bf(float f) {
  u32 u = __float_as_uint(f);
  return (unsigned short)((u + 0x7fffu + ((u >> 16) & 1u)) >> 16);
}
// HW packed conversion: D.lo16 = bf16(a), D.hi16 = bf16(b)
static __device__ __forceinline__ u32 cvtpk(float a, float b) {
  u32 r;
  asm("v_cvt_pk_bf16_f32 %0, %1, %2" : "=v"(r) : "v"(a), "v"(b));
  return r;
}
static __device__ __forceinline__ float lof(u32 h) {  // low bf16 as f32
  return __uint_as_float(h << 16);
}
static __device__ __forceinline__ float hif(u32 h) {  // high bf16 as f32
  return __uint_as_float(h & 0xffff0000u);
}

// ws layout: 32 chunks (256 codes), chunk-major, 51200 B each:
//   [0     ,16384) FragWh : 16 subtiles x 64 lanes x 8 bf16 (A of mfma1, W_hi*KS)
//   [16384 ,32768) FragWl
//   [32768 ,40960) FragCh : 8 PAIRS x 64 lanes x 8 bf16 (A of mfma2, K=32 pairing)
//   [40960 ,49152) FragCl
//   [49152 ,50176) BB fp32[256] (b*KS)   [50176,51200) BT fp32[256] (tp*KS)
// then CC2 fp32[8192]. Total 1671168 B.
// ALL mfma are 16x16x32_bf16 (layout validated by the refcheck'd GEMM ladder).
// mfma1 (logits^T): M=code16, N=tok16, K=32 ([xh;xl]); A repeats W over d=k&15.
// mfma2 (mu^T): M=d16, N=tok16, K=32 over a subtile PAIR (p0=2s, p1=2s+1):
//   k=g*8+j -> code = (j<4 ? p0 : p1)*16 + g*4 + (j&3); B elem j = E[code][tok]
//   which is exactly the e-vector a lane holds from mfma1's D of p0,p1.
__global__ __launch_bounds__(64) void prep_kernel(
    const float* __restrict__ cb, const float* __restrict__ Wm,
    const float* __restrict__ bm, const float* __restrict__ tp,
    char* __restrict__ ws) {
  const int ct = blockIdx.x;  // subtile 0..511 (16 codes)
  const int l = threadIdx.x;
  const int g = l >> 4, q = l & 15;
  const int c = ct >> 4, p = ct & 15;
  const int s = p >> 1, par = p & 1;
  char* chunk = ws + (size_t)c * CHB;
  {  // W fragment (A of mfma1): row=code=ct*16+q, k=g*8+j, d=k&15
    const int code = ct * 16 + q;
    unsigned short wh[8], wl[8];
#pragma unroll
    for (int j = 0; j < 8; j++) {
      int d = (g * 8 + j) & 15;
      float v = Wm[d * VV + code] * KS;
      unsigned short h = f2bf(v);
      wh[j] = h;
      wl[j] = f2bf(v - __uint_as_float((u32)h << 16));
    }
    uint4 hv, lv;
    hv.x = (u32)wh[0] | ((u32)wh[1] << 16); hv.y = (u32)wh[2] | ((u32)wh[3] << 16);
    hv.z = (u32)wh[4] | ((u32)wh[5] << 16); hv.w = (u32)wh[6] | ((u32)wh[7] << 16);
    lv.x = (u32)wl[0] | ((u32)wl[1] << 16); lv.y = (u32)wl[2] | ((u32)wl[3] << 16);
    lv.z = (u32)wl[4] | ((u32)wl[5] << 16); lv.w = (u32)wl[6] | ((u32)wl[7] << 16);
    *(uint4*)(chunk + p * 1024 + l * 16) = hv;
    *(uint4*)(chunk + 16384 + p * 1024 + l * 16) = lv;
  }
  {  // C pair-fragment (A of mfma2): block fills elems par*4+{0..3} of pair s
    unsigned short ch[4], cl_[4];
#pragma unroll
    for (int j = 0; j < 4; j++) {
      int code = ct * 16 + g * 4 + j;
      float v = cb[code * 16 + q];
      unsigned short h = f2bf(v);
      ch[j] = h;
      cl_[j] = f2bf(v - __uint_as_float((u32)h << 16));
    }
    uint2 hv = make_uint2((u32)ch[0] | ((u32)ch[1] << 16),
                          (u32)ch[2] | ((u32)ch[3] << 16));
    uint2 lv = make_uint2((u32)cl_[0] | ((u32)cl_[1] << 16),
                          (u32)cl_[2] | ((u32)cl_[3] << 16));
    *(uint2*)(chunk + 32768 + s * 1024 + l * 16 + par * 8) = hv;
    *(uint2*)(chunk + 40960 + s * 1024 + l * 16 + par * 8) = lv;
  }
  if (l < 16) {
    const int code = ct * 16 + l;
    *(float*)(chunk + 49152 + p * 64 + l * 4) = bm[code] * KS;
    *(float*)(chunk + 50176 + p * 64 + l * 4) = tp[code] * KS;
    float ss = 0.f;
#pragma unroll
    for (int d = 0; d < 16; d++) { float v = cb[code * 16 + d]; ss = fmaf(v, v, ss); }
    *(float*)(ws + WS_CC2B + code * 4) = ss;
  }
}

// R7: issue-slimmed R6. Combined vector pipe was saturated (VALU 81% + MFMA
// 17%); cut VALU instruction count:
//  - __builtin_amdgcn_exp2f (bare v_exp_f32) replaces exp2f libcall+clamp;
//    args bounded (|logit*KS| <~ 12), no denormal/overflow concerns.
//  - bias z rides the mfma1 ACCUMULATOR INIT (D reg j <-> code g*4+j == z
//    lane layout): kills 8 v_add + 8 zero-init movs per TBODY.
// Rest identical to R6: direct L2->VGPR fragment streaming, wave-private
// chunks, named double-buffered regs (rule #20), 2 barriers/phase.
__global__ __launch_bounds__(1024, 4) void flow_kernel(
    const float* __restrict__ x0, const char* __restrict__ ws,
    const float* __restrict__ cb, const int* __restrict__ nsp,
    float* __restrict__ out) {
  __shared__ __align__(16) char smem[108544];
  char* biasL = smem;                       // [32 chunks][2048 B] BB|BT
  float* xT = (float*)(smem + 65536);       // [32][16] base state
  float* xM = (float*)(smem + 67584);       // [32][16] midpoint state
  char* redMp = smem + 69632;               // [16 waves][2 tiles][64] f4 (32 KB)
  float* redL = (float*)(smem + 102400);    // [16][32] lsum partials
  float* redV = (float*)(smem + 104448);    // [16][32] VQ min val
  int* redI = (int*)(smem + 106496);        // [16][32] VQ min idx
  const float* CC2 = (const float*)(ws + WS_CC2B);

  const int tid = threadIdx.x;
  const int lane = tid & 63, wave = tid >> 6;  // 16 waves
  const int s = wave & 7, cpar = wave >> 3;    // pair id, chunk parity
  const int s2 = s * 2;
  const int g = lane >> 4, q = lane & 15;
  const int tok0 = blockIdx.x * 32;

  if (tid < 128)
    *(float4*)(xT + tid * 4) = *(const float4*)(x0 + tok0 * 16 + tid * 4);
  // biases -> LDS once (wave-uniform dst base + lane*16: valid global_load_lds)
#pragma unroll
  for (int sw = 0; sw < 4; sw++) {
    const int c = sw * 8 + (tid >> 7);
    const int off = (tid & 127) * 16;
    __builtin_amdgcn_global_load_lds(
        (const AS1 u32*)(ws + (size_t)c * CHB + 49152 + off),
        (AS3 u32*)(biasL + c * 2048 + off), 16, 0, 0);
  }
  __syncthreads();

  const int n_steps = *nsp;
  const float dt = 1.0f / (float)(n_steps - 1);

  // named double-buffered fragment registers (NO arrays — rule #20)
  s8v aAh0, aAl0, aAh1, aAl1, aCh, aCl;
  s8v bAh0, bAl0, bAh1, bAl1, bCh, bCl;

#define LOADF(P, c) {                                                       \
    const char* _p = ws + (size_t)(c) * CHB;                                \
    P##Ah0 = *(const s8v*)(_p + s2 * 1024 + lane * 16);                     \
    P##Al0 = *(const s8v*)(_p + 16384 + s2 * 1024 + lane * 16);             \
    P##Ah1 = *(const s8v*)(_p + (s2 + 1) * 1024 + lane * 16);               \
    P##Al1 = *(const s8v*)(_p + 16384 + (s2 + 1) * 1024 + lane * 16);       \
    P##Ch = *(const s8v*)(_p + 32768 + s * 1024 + lane * 16);               \
    P##Cl = *(const s8v*)(_p + 40960 + s * 1024 + lane * 16);               \
  }

#define TBODY(AH0, AL0, AH1, AL1, CHF, CLF, BX, MACC, LS, Z0, Z1) {         \
    f4 _D0 = {Z0.x, Z0.y, Z0.z, Z0.w};  /* bias preloaded as C-in */        \
    _D0 = __builtin_amdgcn_mfma_f32_16x16x32_bf16(AH0, BX, _D0, 0, 0, 0);   \
    _D0 = __builtin_amdgcn_mfma_f32_16x16x32_bf16(AL0, BX, _D0, 0, 0, 0);   \
    f4 _D1 = {Z1.x, Z1.y, Z1.z, Z1.w};                                      \
    _D1 = __builtin_amdgcn_mfma_f32_16x16x32_bf16(AH1, BX, _D1, 0, 0, 0);   \
    _D1 = __builtin_amdgcn_mfma_f32_16x16x32_bf16(AL1, BX, _D1, 0, 0, 0);   \
    float _e0 = __builtin_amdgcn_exp2f(_D0[0]);                             \
    float _e1 = __builtin_amdgcn_exp2f(_D0[1]);                             \
    float _e2 = __builtin_amdgcn_exp2f(_D0[2]);                             \
    float _e3 = __builtin_amdgcn_exp2f(_D0[3]);                             \
    float _e4 = __builtin_amdgcn_exp2f(_D1[0]);                             \
    float _e5 = __builtin_amdgcn_exp2f(_D1[1]);                             \
    float _e6 = __builtin_amdgcn_exp2f(_D1[2]);                             \
    float _e7 = __builtin_amdgcn_exp2f(_D1[3]);                             \
    LS += ((_e0 + _e1) + (_e2 + _e3)) + ((_e4 + _e5) + (_e6 + _e7));        \
    union { u32 u[4]; s8v v; } _Eh, _El;                                    \
    _Eh.u[0] = cvtpk(_e0, _e1); _Eh.u[1] = cvtpk(_e2, _e3);                 \
    _Eh.u[2] = cvtpk(_e4, _e5); _Eh.u[3] = cvtpk(_e6, _e7);                 \
    _El.u[0] = cvtpk(_e0 - lof(_Eh.u[0]), _e1 - hif(_Eh.u[0]));             \
    _El.u[1] = cvtpk(_e2 - lof(_Eh.u[1]), _e3 - hif(_Eh.u[1]));             \
    _El.u[2] = cvtpk(_e4 - lof(_Eh.u[2]), _e5 - hif(_Eh.u[2]));             \
    _El.u[3] = cvtpk(_e6 - lof(_Eh.u[3]), _e7 - hif(_Eh.u[3]));             \
    MACC = __builtin_amdgcn_mfma_f32_16x16x32_bf16(CHF, _Eh.v, MACC, 0, 0, 0); \
    MACC = __builtin_amdgcn_mfma_f32_16x16x32_bf16(CHF, _El.v, MACC, 0, 0, 0); \
    MACC = __builtin_amdgcn_mfma_f32_16x16x32_bf16(CLF, _Eh.v, MACC, 0, 0, 0); \
  }

#define COMPUTE(P, c) {                                                     \
    const char* _bias = biasL + (c) * 2048;                                 \
    float4 _bb0 = *(const float4*)(_bias + s2 * 64 + g * 16);               \
    float4 _bt0 = *(const float4*)(_bias + 1024 + s2 * 64 + g * 16);        \
    float4 _bb1 = *(const float4*)(_bias + (s2 + 1) * 64 + g * 16);         \
    float4 _bt1 = *(const float4*)(_bias + 1024 + (s2 + 1) * 64 + g * 16);  \
    float4 _z0, _z1;                                                        \
    _z0.x = fmaf(tt, _bt0.x, _bb0.x); _z0.y = fmaf(tt, _bt0.y, _bb0.y);     \
    _z0.z = fmaf(tt, _bt0.z, _bb0.z); _z0.w = fmaf(tt, _bt0.w, _bb0.w);     \
    _z1.x = fmaf(tt, _bt1.x, _bb1.x); _z1.y = fmaf(tt, _bt1.y, _bb1.y);     \
    _z1.z = fmaf(tt, _bt1.z, _bb1.z); _z1.w = fmaf(tt, _bt1.w, _bb1.w);     \
    TBODY(P##Ah0, P##Al0, P##Ah1, P##Al1, P##Ch, P##Cl, Bx0.v, macc0, ls0,  \
          _z0, _z1);                                                        \
    TBODY(P##Ah0, P##Al0, P##Ah1, P##Al1, P##Ch, P##Cl, Bx1.v, macc1, ls1,  \
          _z0, _z1);                                                        \
  }

  for (int step = 0; step < n_steps - 1; step++) {
#pragma unroll 1
    for (int mh = 0; mh < 2; mh++) {
      const float tt = (float)step * dt + (mh ? 0.5f * dt : 0.0f);
      const float* xsrc = mh ? xM : xT;
      // B-frags of mfma1 for both tiles: col=tok=q, k=g*8+j;
      // k<16 -> xh[d=k], k>=16 -> xl[d=k-16]. Group g covers d=(g&1)*8..+7.
      union { u32 u[4]; s8v v; } Bx0, Bx1;
#pragma unroll
      for (int T = 0; T < 2; T++) {
        const float* xp = xsrc + (T * 16 + q) * 16 + (g & 1) * 8;
        float4 a = *(const float4*)(xp);
        float4 b = *(const float4*)(xp + 4);
        u32 h0 = cvtpk(a.x, a.y), h1 = cvtpk(a.z, a.w);
        u32 h2 = cvtpk(b.x, b.y), h3 = cvtpk(b.z, b.w);
        u32 r0, r1, r2, r3;
        if (g < 2) {
          r0 = h0; r1 = h1; r2 = h2; r3 = h3;
        } else {
          r0 = cvtpk(a.x - lof(h0), a.y - hif(h0));
          r1 = cvtpk(a.z - lof(h1), a.w - hif(h1));
          r2 = cvtpk(b.x - lof(h2), b.y - hif(h2));
          r3 = cvtpk(b.z - lof(h3), b.w - hif(h3));
        }
        if (T == 0) { Bx0.u[0] = r0; Bx0.u[1] = r1; Bx0.u[2] = r2; Bx0.u[3] = r3; }
        else        { Bx1.u[0] = r0; Bx1.u[1] = r1; Bx1.u[2] = r2; Bx1.u[3] = r3; }
      }
      f4 macc0 = {0.f, 0.f, 0.f, 0.f}, macc1 = {0.f, 0.f, 0.f, 0.f};
      float ls0 = 0.f, ls1 = 0.f;

      // chunk pipeline: this wave's 16 chunks {cpar, cpar+2, ...}, 1 ahead
      LOADF(a, cpar);
#pragma unroll 1
      for (int j = 0; j < 16; j += 2) {
        LOADF(b, cpar + 2 * (j + 1));
        COMPUTE(a, cpar + 2 * j);
        if (j + 2 < 16) LOADF(a, cpar + 2 * (j + 2));
        COMPUTE(b, cpar + 2 * (j + 1));
      }

      // partial exchange: lsum reduced over g (lanes q,q+16,q+32,q+48)
      ls0 += __shfl_xor(ls0, 16, 64); ls0 += __shfl_xor(ls0, 32, 64);
      ls1 += __shfl_xor(ls1, 16, 64); ls1 += __shfl_xor(ls1, 32, 64);
      *(f4*)(redMp + ((wave * 2 + 0) * 64 + lane) * 16) = macc0;
      *(f4*)(redMp + ((wave * 2 + 1) * 64 + lane) * 16) = macc1;
      if (lane < 16) {
        redL[wave * 32 + lane] = ls0;
        redL[wave * 32 + 16 + lane] = ls1;
      }
      __syncthreads();
      if ((wave & 7) == 0) {  // waves 0 (tile0) and 8 (tile1) finalize
        const int T2 = wave >> 3;
        f4 m = {0.f, 0.f, 0.f, 0.f};
        float l2 = 0.f;
#pragma unroll
        for (int w = 0; w < 16; w++) {
          f4 o = *(const f4*)(redMp + ((w * 2 + T2) * 64 + lane) * 16);
          m += o;
          l2 += redL[w * 32 + T2 * 16 + q];
        }
        const float inv = 1.0f / fmaxf(l2, 1e-37f);
        const float inv1 = 1.0f / (1.0f - tt + 1e-10f);
        const float cf = (mh == 0) ? (0.5f * dt * inv1) : (dt * inv1);
        // lane owns (tok=q, d=g*4+j) of its tile: contiguous float4
        float4 xb = *(const float4*)(xT + (T2 * 16 + q) * 16 + g * 4);
        float4 xs = mh ? *(const float4*)(xM + (T2 * 16 + q) * 16 + g * 4) : xb;
        float4 xn;
        xn.x = fmaf(cf, m[0] * inv - xs.x, xb.x);
        xn.y = fmaf(cf, m[1] * inv - xs.y, xb.y);
        xn.z = fmaf(cf, m[2] * inv - xs.z, xb.z);
        xn.w = fmaf(cf, m[3] * inv - xs.w, xb.w);
        *(float4*)((mh ? xT : xM) + (T2 * 16 + q) * 16 + g * 4) = xn;
      }
      __syncthreads();
    }
  }

  // ---- outputs: x_final ----
  if (tid < 128)
    *(float4*)(out + tok0 * 16 + tid * 4) = *(const float4*)(xT + tid * 4);

  // ---- VQ argmin: d = ||c||^2 - 2 x.c; wave sweeps its 512 codes for all
  // 32 tokens (4 at a time, fully unrolled: no runtime-indexed arrays). ----
  const int wbase = wave * 512;
#pragma unroll 1
  for (int tg = 0; tg < 8; tg++) {
    float xr[4][16];
#pragma unroll
    for (int t = 0; t < 4; t++)
#pragma unroll
      for (int d4 = 0; d4 < 4; d4++)
        *(float4*)(&xr[t][d4 * 4]) = *(const float4*)(xT + (tg * 4 + t) * 16 + d4 * 4);
    float mv[4] = {3.402823466e38f, 3.402823466e38f, 3.402823466e38f, 3.402823466e38f};
    int mi[4] = {0, 0, 0, 0};
#pragma unroll 1
    for (int i = 0; i < 8; i++) {
      const int code = wbase + i * 64 + lane;
      float cr[16];
#pragma unroll
      for (int d4 = 0; d4 < 4; d4++)
        *(float4*)(&cr[d4 * 4]) = *(const float4*)(cb + code * 16 + d4 * 4);
      const float cc = CC2[code];
#pragma unroll
      for (int t = 0; t < 4; t++) {
        float dot = 0.f;
#pragma unroll
        for (int d = 0; d < 16; d++) dot = fmaf(xr[t][d], cr[d], dot);
        float dist = fmaf(-2.f, dot, cc);
        if (dist < mv[t]) { mv[t] = dist; mi[t] = code; }
      }
    }
#pragma unroll
    for (int t = 0; t < 4; t++) {
#pragma unroll
      for (int m = 1; m < 64; m <<= 1) {
        float ov = __shfl_xor(mv[t], m, 64);
        int oi = __shfl_xor(mi[t], m, 64);
        if (ov < mv[t] || (ov == mv[t] && oi < mi[t])) { mv[t] = ov; mi[t] = oi; }
      }
      if (lane == 0) {
        redV[wave * 32 + tg * 4 + t] = mv[t];
        redI[wave * 32 + tg * 4 + t] = mi[t];
      }
    }
  }
  __syncthreads();
  if (tid < 32) {
    float bv = redV[tid];
    int bi = redI[tid];
#pragma unroll
    for (int w = 1; w < 16; w++) {
      float ov = redV[w * 32 + tid];
      int oi = redI[w * 32 + tid];
      if (ov < bv || (ov == bv && oi < bi)) { bv = ov; bi = oi; }
    }
    out[NTOK * 16 + tok0 + tid] = (float)bi;
  }
}

extern "C" void kernel_launch(void* const* d_in, const int* in_sizes, int n_in,
                              void* d_out, int out_size, void* d_ws, size_t ws_size,
                              hipStream_t stream) {
  const float* x0 = (const float*)d_in[0];
  const float* cb = (const float*)d_in[1];
  const float* Wm = (const float*)d_in[2];
  const float* bm = (const float*)d_in[3];
  const float* tp = (const float*)d_in[4];
  const int* ns = (const int*)d_in[5];
  char* ws = (char*)d_ws;  // needs 1671168 B
  float* out = (float*)d_out;

  prep_kernel<<<512, 64, 0, stream>>>(cb, Wm, bm, tp, ws);
  flow_kernel<<<256, 1024, 0, stream>>>(x0, ws, cb, ns, out);
}

// Round 8
// 413.205 us; speedup vs baseline: 3.2252x; 1.0538x over previous
//
#include <hip/hip_runtime.h>

#define KS 1.8033688011112042f  // log2(e)/0.8
#define NTOK 8192
#define VV 8192
#define CHB 51200
#define WS_CC2B 1638400

typedef float f4 __attribute__((ext_vector_type(4)));
typedef short s8v __attribute__((ext_vector_type(8)));
typedef unsigned int u32;
#define AS1 __attribute__((address_space(1)))
#define AS3 __attribute__((address_space(3)))

// RNE float->bf16, bit-ops (prep only — cold)
static __device__ __forceinline__ unsigned short f2bf(float f) {
  u32 u = __float_as_uint(f);
  return (unsigned short)((u + 0x7fffu + ((u >> 16) & 1u)) >> 16);
}
// HW packed conversion: D.lo16 = bf16(a), D.hi16 = bf16(b)
static __device__ __forceinline__ u32 cvtpk(float a, float b) {
  u32 r;
  asm("v_cvt_pk_bf16_f32 %0, %1, %2" : "=v"(r) : "v"(a), "v"(b));
  return r;
}
static __device__ __forceinline__ float lof(u32 h) {  // low bf16 as f32
  return __uint_as_float(h << 16);
}
static __device__ __forceinline__ float hif(u32 h) {  // high bf16 as f32
  return __uint_as_float(h & 0xffff0000u);
}

// ws layout: 32 chunks (256 codes), chunk-major, 51200 B each:
//   [0     ,16384) FragWh : 16 subtiles x 64 lanes x 8 bf16 (A of mfma1, W_hi*KS)
//   [16384 ,32768) FragWl
//   [32768 ,40960) FragCh : 8 PAIRS x 64 lanes x 8 bf16 (A of mfma2, K=32 pairing)
//   [40960 ,49152) FragCl
//   [49152 ,50176) BB fp32[256] (b*KS)   [50176,51200) BT fp32[256] (tp*KS)
// then CC2 fp32[8192]. Total 1671168 B.
// ALL mfma are 16x16x32_bf16 (layout validated by the refcheck'd GEMM ladder).
// mfma1 (logits^T): M=code16, N=tok16, K=32 ([xh;xl]); A repeats W over d=k&15.
// mfma2 (mu^T): M=d16, N=tok16, K=32 over a subtile PAIR (p0=2s, p1=2s+1):
//   k=g*8+j -> code = (j<4 ? p0 : p1)*16 + g*4 + (j&3); B elem j = E[code][tok]
//   which is exactly the e-vector a lane holds from mfma1's D of p0,p1.
__global__ __launch_bounds__(64) void prep_kernel(
    const float* __restrict__ cb, const float* __restrict__ Wm,
    const float* __restrict__ bm, const float* __restrict__ tp,
    char* __restrict__ ws) {
  const int ct = blockIdx.x;  // subtile 0..511 (16 codes)
  const int l = threadIdx.x;
  const int g = l >> 4, q = l & 15;
  const int c = ct >> 4, p = ct & 15;
  const int s = p >> 1, par = p & 1;
  char* chunk = ws + (size_t)c * CHB;
  {  // W fragment (A of mfma1): row=code=ct*16+q, k=g*8+j, d=k&15
    const int code = ct * 16 + q;
    unsigned short wh[8], wl[8];
#pragma unroll
    for (int j = 0; j < 8; j++) {
      int d = (g * 8 + j) & 15;
      float v = Wm[d * VV + code] * KS;
      unsigned short h = f2bf(v);
      wh[j] = h;
      wl[j] = f2bf(v - __uint_as_float((u32)h << 16));
    }
    uint4 hv, lv;
    hv.x = (u32)wh[0] | ((u32)wh[1] << 16); hv.y = (u32)wh[2] | ((u32)wh[3] << 16);
    hv.z = (u32)wh[4] | ((u32)wh[5] << 16); hv.w = (u32)wh[6] | ((u32)wh[7] << 16);
    lv.x = (u32)wl[0] | ((u32)wl[1] << 16); lv.y = (u32)wl[2] | ((u32)wl[3] << 16);
    lv.z = (u32)wl[4] | ((u32)wl[5] << 16); lv.w = (u32)wl[6] | ((u32)wl[7] << 16);
    *(uint4*)(chunk + p * 1024 + l * 16) = hv;
    *(uint4*)(chunk + 16384 + p * 1024 + l * 16) = lv;
  }
  {  // C pair-fragment (A of mfma2): block fills elems par*4+{0..3} of pair s
    unsigned short ch[4], cl_[4];
#pragma unroll
    for (int j = 0; j < 4; j++) {
      int code = ct * 16 + g * 4 + j;
      float v = cb[code * 16 + q];
      unsigned short h = f2bf(v);
      ch[j] = h;
      cl_[j] = f2bf(v - __uint_as_float((u32)h << 16));
    }
    uint2 hv = make_uint2((u32)ch[0] | ((u32)ch[1] << 16),
                          (u32)ch[2] | ((u32)ch[3] << 16));
    uint2 lv = make_uint2((u32)cl_[0] | ((u32)cl_[1] << 16),
                          (u32)cl_[2] | ((u32)cl_[3] << 16));
    *(uint2*)(chunk + 32768 + s * 1024 + l * 16 + par * 8) = hv;
    *(uint2*)(chunk + 40960 + s * 1024 + l * 16 + par * 8) = lv;
  }
  if (l < 16) {
    const int code = ct * 16 + l;
    *(float*)(chunk + 49152 + p * 64 + l * 4) = bm[code] * KS;
    *(float*)(chunk + 50176 + p * 64 + l * 4) = tp[code] * KS;
    float ss = 0.f;
#pragma unroll
    for (int d = 0; d < 16; d++) { float v = cb[code * 16 + d]; ss = fmaf(v, v, ss); }
    *(float*)(ws + WS_CC2B + code * 4) = ss;
  }
}

// R8: VALU->MFMA work shift on top of R7.
//  - zL table: z = bb + tt*bt for ALL 8192 codes computed ONCE per phase into
//    LDS (fill overlapped with the finalize serial window); COMPUTE does 2
//    broadcast ds_reads, no per-chunk fmafs.
//  - lsum via ones-MFMA: mfma(ones, Eh/El, lacc) gives Sum_k E[k][tok] in the
//    accumulator (every D row = pair sum) -> kills 16 adds/chunk + phase-end
//    g-reduction shuffles; rides the idle matrix pipe.
// Rest identical to R7: direct L2->VGPR fragment streaming, wave-private
// chunks, named double-buffered regs (rule #20), 2 barriers/phase.
__global__ __launch_bounds__(1024, 4) void flow_kernel(
    const float* __restrict__ x0, const char* __restrict__ ws,
    const float* __restrict__ cb, const int* __restrict__ nsp,
    float* __restrict__ out) {
  __shared__ __align__(16) char smem[141312];
  char* biasL = smem;                       // [32 chunks][2048 B] BB|BT
  float* xT = (float*)(smem + 65536);       // [32][16] base state
  float* xM = (float*)(smem + 67584);       // [32][16] midpoint state
  char* redMp = smem + 69632;               // [16 waves][2 tiles][64] f4 (32 KB)
  float* redL = (float*)(smem + 102400);    // [16][32] lsum partials
  float* redV = (float*)(smem + 104448);    // [16][32] VQ min val
  int* redI = (int*)(smem + 106496);        // [16][32] VQ min idx
  float* zL = (float*)(smem + 108544);      // [32 chunks][256] z table (32 KB)
  const float* CC2 = (const float*)(ws + WS_CC2B);

  const int tid = threadIdx.x;
  const int lane = tid & 63, wave = tid >> 6;  // 16 waves
  const int s = wave & 7, cpar = wave >> 3;    // pair id, chunk parity
  const int s2 = s * 2;
  const int g = lane >> 4, q = lane & 15;
  const int tok0 = blockIdx.x * 32;

  if (tid < 128)
    *(float4*)(xT + tid * 4) = *(const float4*)(x0 + tok0 * 16 + tid * 4);
  // biases -> LDS once (wave-uniform dst base + lane*16: valid global_load_lds)
#pragma unroll
  for (int sw = 0; sw < 4; sw++) {
    const int c = sw * 8 + (tid >> 7);
    const int off = (tid & 127) * 16;
    __builtin_amdgcn_global_load_lds(
        (const AS1 u32*)(ws + (size_t)c * CHB + 49152 + off),
        (AS3 u32*)(biasL + c * 2048 + off), 16, 0, 0);
  }
  __syncthreads();

  const int n_steps = *nsp;
  const float dt = 1.0f / (float)(n_steps - 1);

  // ones A-fragment for the lsum MFMA
  union { u32 u[4]; s8v v; } ONES;
  ONES.u[0] = ONES.u[1] = ONES.u[2] = ONES.u[3] = 0x3f803f80u;

  // named double-buffered fragment registers (NO arrays — rule #20)
  s8v aAh0, aAl0, aAh1, aAl1, aCh, aCl;
  s8v bAh0, bAl0, bAh1, bAl1, bCh, bCl;

#define ZFILL(TT) {                                                         \
    const int _c = tid >> 5;                                                \
    const int _i = (tid & 31) << 3;                                         \
    const char* _bp = biasL + _c * 2048 + _i * 4;                           \
    float4 _b0 = *(const float4*)(_bp);                                     \
    float4 _b1 = *(const float4*)(_bp + 16);                                \
    float4 _t0 = *(const float4*)(_bp + 1024);                              \
    float4 _t1 = *(const float4*)(_bp + 1040);                              \
    float4 _za, _zb;                                                        \
    _za.x = fmaf(TT, _t0.x, _b0.x); _za.y = fmaf(TT, _t0.y, _b0.y);         \
    _za.z = fmaf(TT, _t0.z, _b0.z); _za.w = fmaf(TT, _t0.w, _b0.w);         \
    _zb.x = fmaf(TT, _t1.x, _b1.x); _zb.y = fmaf(TT, _t1.y, _b1.y);         \
    _zb.z = fmaf(TT, _t1.z, _b1.z); _zb.w = fmaf(TT, _t1.w, _b1.w);         \
    *(float4*)(zL + _c * 256 + _i) = _za;                                   \
    *(float4*)(zL + _c * 256 + _i + 4) = _zb;                               \
  }

#define LOADF(P, c) {                                                       \
    const char* _p = ws + (size_t)(c) * CHB;                                \
    P##Ah0 = *(const s8v*)(_p + s2 * 1024 + lane * 16);                     \
    P##Al0 = *(const s8v*)(_p + 16384 + s2 * 1024 + lane * 16);             \
    P##Ah1 = *(const s8v*)(_p + (s2 + 1) * 1024 + lane * 16);               \
    P##Al1 = *(const s8v*)(_p + 16384 + (s2 + 1) * 1024 + lane * 16);       \
    P##Ch = *(const s8v*)(_p + 32768 + s * 1024 + lane * 16);               \
    P##Cl = *(const s8v*)(_p + 40960 + s * 1024 + lane * 16);               \
  }

#define TBODY(AH0, AL0, AH1, AL1, CHF, CLF, BX, MACC, LACC, Z0, Z1) {       \
    f4 _D0 = {Z0.x, Z0.y, Z0.z, Z0.w};  /* bias preloaded as C-in */        \
    _D0 = __builtin_amdgcn_mfma_f32_16x16x32_bf16(AH0, BX, _D0, 0, 0, 0);   \
    _D0 = __builtin_amdgcn_mfma_f32_16x16x32_bf16(AL0, BX, _D0, 0, 0, 0);   \
    f4 _D1 = {Z1.x, Z1.y, Z1.z, Z1.w};                                      \
    _D1 = __builtin_amdgcn_mfma_f32_16x16x32_bf16(AH1, BX, _D1, 0, 0, 0);   \
    _D1 = __builtin_amdgcn_mfma_f32_16x16x32_bf16(AL1, BX, _D1, 0, 0, 0);   \
    float _e0 = __builtin_amdgcn_exp2f(_D0[0]);                             \
    float _e1 = __builtin_amdgcn_exp2f(_D0[1]);                             \
    float _e2 = __builtin_amdgcn_exp2f(_D0[2]);                             \
    float _e3 = __builtin_amdgcn_exp2f(_D0[3]);                             \
    float _e4 = __builtin_amdgcn_exp2f(_D1[0]);                             \
    float _e5 = __builtin_amdgcn_exp2f(_D1[1]);                             \
    float _e6 = __builtin_amdgcn_exp2f(_D1[2]);                             \
    float _e7 = __builtin_amdgcn_exp2f(_D1[3]);                             \
    union { u32 u[4]; s8v v; } _Eh, _El;                                    \
    _Eh.u[0] = cvtpk(_e0, _e1); _Eh.u[1] = cvtpk(_e2, _e3);                 \
    _Eh.u[2] = cvtpk(_e4, _e5); _Eh.u[3] = cvtpk(_e6, _e7);                 \
    _El.u[0] = cvtpk(_e0 - lof(_Eh.u[0]), _e1 - hif(_Eh.u[0]));             \
    _El.u[1] = cvtpk(_e2 - lof(_Eh.u[1]), _e3 - hif(_Eh.u[1]));             \
    _El.u[2] = cvtpk(_e4 - lof(_Eh.u[2]), _e5 - hif(_Eh.u[2]));             \
    _El.u[3] = cvtpk(_e6 - lof(_Eh.u[3]), _e7 - hif(_Eh.u[3]));             \
    MACC = __builtin_amdgcn_mfma_f32_16x16x32_bf16(CHF, _Eh.v, MACC, 0, 0, 0); \
    MACC = __builtin_amdgcn_mfma_f32_16x16x32_bf16(CHF, _El.v, MACC, 0, 0, 0); \
    MACC = __builtin_amdgcn_mfma_f32_16x16x32_bf16(CLF, _Eh.v, MACC, 0, 0, 0); \
    LACC = __builtin_amdgcn_mfma_f32_16x16x32_bf16(ONES.v, _Eh.v, LACC, 0, 0, 0); \
    LACC = __builtin_amdgcn_mfma_f32_16x16x32_bf16(ONES.v, _El.v, LACC, 0, 0, 0); \
  }

#define COMPUTE(P, c) {                                                     \
    const float* _zp = zL + (c) * 256 + s2 * 16 + g * 4;                    \
    float4 _z0 = *(const float4*)(_zp);                                     \
    float4 _z1 = *(const float4*)(_zp + 16);                                \
    TBODY(P##Ah0, P##Al0, P##Ah1, P##Al1, P##Ch, P##Cl, Bx0.v, macc0,       \
          lacc0, _z0, _z1);                                                 \
    TBODY(P##Ah0, P##Al0, P##Ah1, P##Al1, P##Ch, P##Cl, Bx1.v, macc1,       \
          lacc1, _z0, _z1);                                                 \
  }

  // prologue: z table for phase 0 (tt = 0)
  ZFILL(0.0f);
  __syncthreads();

  for (int step = 0; step < n_steps - 1; step++) {
#pragma unroll 1
    for (int mh = 0; mh < 2; mh++) {
      const float tt = (float)step * dt + (mh ? 0.5f * dt : 0.0f);
      const float* xsrc = mh ? xM : xT;
      // B-frags of mfma1 for both tiles: col=tok=q, k=g*8+j;
      // k<16 -> xh[d=k], k>=16 -> xl[d=k-16]. Group g covers d=(g&1)*8..+7.
      union { u32 u[4]; s8v v; } Bx0, Bx1;
#pragma unroll
      for (int T = 0; T < 2; T++) {
        const float* xp = xsrc + (T * 16 + q) * 16 + (g & 1) * 8;
        float4 a = *(const float4*)(xp);
        float4 b = *(const float4*)(xp + 4);
        u32 h0 = cvtpk(a.x, a.y), h1 = cvtpk(a.z, a.w);
        u32 h2 = cvtpk(b.x, b.y), h3 = cvtpk(b.z, b.w);
        u32 r0, r1, r2, r3;
        if (g < 2) {
          r0 = h0; r1 = h1; r2 = h2; r3 = h3;
        } else {
          r0 = cvtpk(a.x - lof(h0), a.y - hif(h0));
          r1 = cvtpk(a.z - lof(h1), a.w - hif(h1));
          r2 = cvtpk(b.x - lof(h2), b.y - hif(h2));
          r3 = cvtpk(b.z - lof(h3), b.w - hif(h3));
        }
        if (T == 0) { Bx0.u[0] = r0; Bx0.u[1] = r1; Bx0.u[2] = r2; Bx0.u[3] = r3; }
        else        { Bx1.u[0] = r0; Bx1.u[1] = r1; Bx1.u[2] = r2; Bx1.u[3] = r3; }
      }
      f4 macc0 = {0.f, 0.f, 0.f, 0.f}, macc1 = {0.f, 0.f, 0.f, 0.f};
      f4 lacc0 = {0.f, 0.f, 0.f, 0.f}, lacc1 = {0.f, 0.f, 0.f, 0.f};

      // chunk pipeline: this wave's 16 chunks {cpar, cpar+2, ...}, 1 ahead
      LOADF(a, cpar);
#pragma unroll 1
      for (int j = 0; j < 16; j += 2) {
        LOADF(b, cpar + 2 * (j + 1));
        COMPUTE(a, cpar + 2 * j);
        if (j + 2 < 16) LOADF(a, cpar + 2 * (j + 2));
        COMPUTE(b, cpar + 2 * (j + 1));
      }

      // partials: macc per lane; lsum complete per tok in lacc (any row reg)
      *(f4*)(redMp + ((wave * 2 + 0) * 64 + lane) * 16) = macc0;
      *(f4*)(redMp + ((wave * 2 + 1) * 64 + lane) * 16) = macc1;
      if (lane < 16) {
        redL[wave * 32 + lane] = lacc0[0];
        redL[wave * 32 + 16 + lane] = lacc1[0];
      }
      __syncthreads();
      // z table for the NEXT phase — overlaps the finalize serial window
      const float ttn = (mh == 0) ? (tt + 0.5f * dt) : ((float)(step + 1) * dt);
      ZFILL(ttn);
      if ((wave & 7) == 0) {  // waves 0 (tile0) and 8 (tile1) finalize
        const int T2 = wave >> 3;
        f4 m = {0.f, 0.f, 0.f, 0.f};
        float l2 = 0.f;
#pragma unroll
        for (int w = 0; w < 16; w++) {
          f4 o = *(const f4*)(redMp + ((w * 2 + T2) * 64 + lane) * 16);
          m += o;
          l2 += redL[w * 32 + T2 * 16 + q];
        }
        const float inv = 1.0f / fmaxf(l2, 1e-37f);
        const float inv1 = 1.0f / (1.0f - tt + 1e-10f);
        const float cf = (mh == 0) ? (0.5f * dt * inv1) : (dt * inv1);
        // lane owns (tok=q, d=g*4+j) of its tile: contiguous float4
        float4 xb = *(const float4*)(xT + (T2 * 16 + q) * 16 + g * 4);
        float4 xs = mh ? *(const float4*)(xM + (T2 * 16 + q) * 16 + g * 4) : xb;
        float4 xn;
        xn.x = fmaf(cf, m[0] * inv - xs.x, xb.x);
        xn.y = fmaf(cf, m[1] * inv - xs.y, xb.y);
        xn.z = fmaf(cf, m[2] * inv - xs.z, xb.z);
        xn.w = fmaf(cf, m[3] * inv - xs.w, xb.w);
        *(float4*)((mh ? xT : xM) + (T2 * 16 + q) * 16 + g * 4) = xn;
      }
      __syncthreads();
    }
  }

  // ---- outputs: x_final ----
  if (tid < 128)
    *(float4*)(out + tok0 * 16 + tid * 4) = *(const float4*)(xT + tid * 4);

  // ---- VQ argmin: d = ||c||^2 - 2 x.c; wave sweeps its 512 codes for all
  // 32 tokens (4 at a time, fully unrolled: no runtime-indexed arrays). ----
  const int wbase = wave * 512;
#pragma unroll 1
  for (int tg = 0; tg < 8; tg++) {
    float xr[4][16];
#pragma unroll
    for (int t = 0; t < 4; t++)
#pragma unroll
      for (int d4 = 0; d4 < 4; d4++)
        *(float4*)(&xr[t][d4 * 4]) = *(const float4*)(xT + (tg * 4 + t) * 16 + d4 * 4);
    float mv[4] = {3.402823466e38f, 3.402823466e38f, 3.402823466e38f, 3.402823466e38f};
    int mi[4] = {0, 0, 0, 0};
#pragma unroll 1
    for (int i = 0; i < 8; i++) {
      const int code = wbase + i * 64 + lane;
      float cr[16];
#pragma unroll
      for (int d4 = 0; d4 < 4; d4++)
        *(float4*)(&cr[d4 * 4]) = *(const float4*)(cb + code * 16 + d4 * 4);
      const float cc = CC2[code];
#pragma unroll
      for (int t = 0; t < 4; t++) {
        float dot = 0.f;
#pragma unroll
        for (int d = 0; d < 16; d++) dot = fmaf(xr[t][d], cr[d], dot);
        float dist = fmaf(-2.f, dot, cc);
        if (dist < mv[t]) { mv[t] = dist; mi[t] = code; }
      }
    }
#pragma unroll
    for (int t = 0; t < 4; t++) {
#pragma unroll
      for (int m = 1; m < 64; m <<= 1) {
        float ov = __shfl_xor(mv[t], m, 64);
        int oi = __shfl_xor(mi[t], m, 64);
        if (ov < mv[t] || (ov == mv[t] && oi < mi[t])) { mv[t] = ov; mi[t] = oi; }
      }
      if (lane == 0) {
        redV[wave * 32 + tg * 4 + t] = mv[t];
        redI[wave * 32 + tg * 4 + t] = mi[t];
      }
    }
  }
  __syncthreads();
  if (tid < 32) {
    float bv = redV[tid];
    int bi = redI[tid];
#pragma unroll
    for (int w = 1; w < 16; w++) {
      float ov = redV[w * 32 + tid];
      int oi = redI[w * 32 + tid];
      if (ov < bv || (ov == bv && oi < bi)) { bv = ov; bi = oi; }
    }
    out[NTOK * 16 + tok0 + tid] = (float)bi;
  }
}

extern "C" void kernel_launch(void* const* d_in, const int* in_sizes, int n_in,
                              void* d_out, int out_size, void* d_ws, size_t ws_size,
                              hipStream_t stream) {
  const float* x0 = (const float*)d_in[0];
  const float* cb = (const float*)d_in[1];
  const float* Wm = (const float*)d_in[2];
  const float* bm = (const float*)d_in[3];
  const float* tp = (const float*)d_in[4];
  const int* ns = (const int*)d_in[5];
  char* ws = (char*)d_ws;  // needs 1671168 B
  float* out = (float*)d_out;

  prep_kernel<<<512, 64, 0, stream>>>(cb, Wm, bm, tp, ws);
  flow_kernel<<<256, 1024, 0, stream>>>(x0, ws, cb, ns, out);
}

// Round 9
// 357.682 us; speedup vs baseline: 3.7259x; 1.1552x over previous
//
#include <hip/hip_runtime.h>

#define KS 1.8033688011112042f  // log2(e)/0.8
#define NTOK 8192
#define VV 8192
#define CHB 51200
#define WS_CC2B 1638400

typedef float f4 __attribute__((ext_vector_type(4)));
typedef short s8v __attribute__((ext_vector_type(8)));
typedef unsigned int u32;
#define AS1 __attribute__((address_space(1)))
#define AS3 __attribute__((address_space(3)))

// RNE float->bf16, bit-ops (prep only — cold)
static __device__ __forceinline__ unsigned short f2bf(float f) {
  u32 u = __float_as_uint(f);
  return (unsigned short)((u + 0x7fffu + ((u >> 16) & 1u)) >> 16);
}
// HW packed conversion: D.lo16 = bf16(a), D.hi16 = bf16(b)
static __device__ __forceinline__ u32 cvtpk(float a, float b) {
  u32 r;
  asm("v_cvt_pk_bf16_f32 %0, %1, %2" : "=v"(r) : "v"(a), "v"(b));
  return r;
}
static __device__ __forceinline__ float lof(u32 h) {  // low bf16 as f32
  return __uint_as_float(h << 16);
}
static __device__ __forceinline__ float hif(u32 h) {  // high bf16 as f32
  return __uint_as_float(h & 0xffff0000u);
}

// ws layout: 32 chunks (256 codes), chunk-major, 51200 B each:
//   [0     ,16384) FragWh : 16 subtiles x 64 lanes x 8 bf16 (A of mfma1, W_hi*KS)
//   [16384 ,32768) FragWl
//   [32768 ,40960) FragCh : 8 PAIRS x 64 lanes x 8 bf16 (A of mfma2, K=32 pairing)
//   [40960 ,49152) FragCl
//   [49152 ,50176) BB fp32[256] (b*KS)   [50176,51200) BT fp32[256] (tp*KS)
// then CC2 fp32[8192]. Total 1671168 B.
// ALL mfma are 16x16x32_bf16 (layout validated by the refcheck'd GEMM ladder).
// mfma1 (logits^T): M=code16, N=tok16, K=32 ([xh;xl]); A repeats W over d=k&15.
// mfma2 (mu^T): M=d16, N=tok16, K=32 over a subtile PAIR (p0=2s, p1=2s+1):
//   k=g*8+j -> code = (j<4 ? p0 : p1)*16 + g*4 + (j&3); B elem j = E[code][tok]
//   which is exactly the e-vector a lane holds from mfma1's D of p0,p1.
__global__ __launch_bounds__(64) void prep_kernel(
    const float* __restrict__ cb, const float* __restrict__ Wm,
    const float* __restrict__ bm, const float* __restrict__ tp,
    char* __restrict__ ws) {
  const int ct = blockIdx.x;  // subtile 0..511 (16 codes)
  const int l = threadIdx.x;
  const int g = l >> 4, q = l & 15;
  const int c = ct >> 4, p = ct & 15;
  const int s = p >> 1, par = p & 1;
  char* chunk = ws + (size_t)c * CHB;
  {  // W fragment (A of mfma1): row=code=ct*16+q, k=g*8+j, d=k&15
    const int code = ct * 16 + q;
    unsigned short wh[8], wl[8];
#pragma unroll
    for (int j = 0; j < 8; j++) {
      int d = (g * 8 + j) & 15;
      float v = Wm[d * VV + code] * KS;
      unsigned short h = f2bf(v);
      wh[j] = h;
      wl[j] = f2bf(v - __uint_as_float((u32)h << 16));
    }
    uint4 hv, lv;
    hv.x = (u32)wh[0] | ((u32)wh[1] << 16); hv.y = (u32)wh[2] | ((u32)wh[3] << 16);
    hv.z = (u32)wh[4] | ((u32)wh[5] << 16); hv.w = (u32)wh[6] | ((u32)wh[7] << 16);
    lv.x = (u32)wl[0] | ((u32)wl[1] << 16); lv.y = (u32)wl[2] | ((u32)wl[3] << 16);
    lv.z = (u32)wl[4] | ((u32)wl[5] << 16); lv.w = (u32)wl[6] | ((u32)wl[7] << 16);
    *(uint4*)(chunk + p * 1024 + l * 16) = hv;
    *(uint4*)(chunk + 16384 + p * 1024 + l * 16) = lv;
  }
  {  // C pair-fragment (A of mfma2): block fills elems par*4+{0..3} of pair s
    unsigned short ch[4], cl_[4];
#pragma unroll
    for (int j = 0; j < 4; j++) {
      int code = ct * 16 + g * 4 + j;
      float v = cb[code * 16 + q];
      unsigned short h = f2bf(v);
      ch[j] = h;
      cl_[j] = f2bf(v - __uint_as_float((u32)h << 16));
    }
    uint2 hv = make_uint2((u32)ch[0] | ((u32)ch[1] << 16),
                          (u32)ch[2] | ((u32)ch[3] << 16));
    uint2 lv = make_uint2((u32)cl_[0] | ((u32)cl_[1] << 16),
                          (u32)cl_[2] | ((u32)cl_[3] << 16));
    *(uint2*)(chunk + 32768 + s * 1024 + l * 16 + par * 8) = hv;
    *(uint2*)(chunk + 40960 + s * 1024 + l * 16 + par * 8) = lv;
  }
  if (l < 16) {
    const int code = ct * 16 + l;
    *(float*)(chunk + 49152 + p * 64 + l * 4) = bm[code] * KS;
    *(float*)(chunk + 50176 + p * 64 + l * 4) = tp[code] * KS;
    float ss = 0.f;
#pragma unroll
    for (int d = 0; d < 16; d++) { float v = cb[code * 16 + d]; ss = fmaf(v, v, ss); }
    *(float*)(ws + WS_CC2B + code * 4) = ss;
  }
}

// R9: drop the E-residual (El) path. mu is a linear average — RNE errors of
// bf16(E) (<=2^-9 rel, random sign) cancel stochastically; the exp-sensitive
// LOGIT path keeps its full W/x hi+lo split. Cl*Eh retained (1 idle-pipe MFMA,
// 0 VALU) to halve the dropped-term error. TBODY: 32->12 VALU (8 exp +
// 4 cvtpk), 9->7 MFMA. R8's 91% combined-issue saturation said: remove work.
// Rest identical to R8: zL table, lsum ones-MFMA, direct L2->VGPR streaming,
// wave-private chunks, named double-buffered regs (rule #20), 2 barriers/phase.
__global__ __launch_bounds__(1024, 4) void flow_kernel(
    const float* __restrict__ x0, const char* __restrict__ ws,
    const float* __restrict__ cb, const int* __restrict__ nsp,
    float* __restrict__ out) {
  __shared__ __align__(16) char smem[141312];
  char* biasL = smem;                       // [32 chunks][2048 B] BB|BT
  float* xT = (float*)(smem + 65536);       // [32][16] base state
  float* xM = (float*)(smem + 67584);       // [32][16] midpoint state
  char* redMp = smem + 69632;               // [16 waves][2 tiles][64] f4 (32 KB)
  float* redL = (float*)(smem + 102400);    // [16][32] lsum partials
  float* redV = (float*)(smem + 104448);    // [16][32] VQ min val
  int* redI = (int*)(smem + 106496);        // [16][32] VQ min idx
  float* zL = (float*)(smem + 108544);      // [32 chunks][256] z table (32 KB)
  const float* CC2 = (const float*)(ws + WS_CC2B);

  const int tid = threadIdx.x;
  const int lane = tid & 63, wave = tid >> 6;  // 16 waves
  const int s = wave & 7, cpar = wave >> 3;    // pair id, chunk parity
  const int s2 = s * 2;
  const int g = lane >> 4, q = lane & 15;
  const int tok0 = blockIdx.x * 32;

  if (tid < 128)
    *(float4*)(xT + tid * 4) = *(const float4*)(x0 + tok0 * 16 + tid * 4);
  // biases -> LDS once (wave-uniform dst base + lane*16: valid global_load_lds)
#pragma unroll
  for (int sw = 0; sw < 4; sw++) {
    const int c = sw * 8 + (tid >> 7);
    const int off = (tid & 127) * 16;
    __builtin_amdgcn_global_load_lds(
        (const AS1 u32*)(ws + (size_t)c * CHB + 49152 + off),
        (AS3 u32*)(biasL + c * 2048 + off), 16, 0, 0);
  }
  __syncthreads();

  const int n_steps = *nsp;
  const float dt = 1.0f / (float)(n_steps - 1);

  // ones A-fragment for the lsum MFMA
  union { u32 u[4]; s8v v; } ONES;
  ONES.u[0] = ONES.u[1] = ONES.u[2] = ONES.u[3] = 0x3f803f80u;

  // named double-buffered fragment registers (NO arrays — rule #20)
  s8v aAh0, aAl0, aAh1, aAl1, aCh, aCl;
  s8v bAh0, bAl0, bAh1, bAl1, bCh, bCl;

#define ZFILL(TT) {                                                         \
    const int _c = tid >> 5;                                                \
    const int _i = (tid & 31) << 3;                                         \
    const char* _bp = biasL + _c * 2048 + _i * 4;                           \
    float4 _b0 = *(const float4*)(_bp);                                     \
    float4 _b1 = *(const float4*)(_bp + 16);                                \
    float4 _t0 = *(const float4*)(_bp + 1024);                              \
    float4 _t1 = *(const float4*)(_bp + 1040);                              \
    float4 _za, _zb;                                                        \
    _za.x = fmaf(TT, _t0.x, _b0.x); _za.y = fmaf(TT, _t0.y, _b0.y);         \
    _za.z = fmaf(TT, _t0.z, _b0.z); _za.w = fmaf(TT, _t0.w, _b0.w);         \
    _zb.x = fmaf(TT, _t1.x, _b1.x); _zb.y = fmaf(TT, _t1.y, _b1.y);         \
    _zb.z = fmaf(TT, _t1.z, _b1.z); _zb.w = fmaf(TT, _t1.w, _b1.w);         \
    *(float4*)(zL + _c * 256 + _i) = _za;                                   \
    *(float4*)(zL + _c * 256 + _i + 4) = _zb;                               \
  }

#define LOADF(P, c) {                                                       \
    const char* _p = ws + (size_t)(c) * CHB;                                \
    P##Ah0 = *(const s8v*)(_p + s2 * 1024 + lane * 16);                     \
    P##Al0 = *(const s8v*)(_p + 16384 + s2 * 1024 + lane * 16);             \
    P##Ah1 = *(const s8v*)(_p + (s2 + 1) * 1024 + lane * 16);               \
    P##Al1 = *(const s8v*)(_p + 16384 + (s2 + 1) * 1024 + lane * 16);       \
    P##Ch = *(const s8v*)(_p + 32768 + s * 1024 + lane * 16);               \
    P##Cl = *(const s8v*)(_p + 40960 + s * 1024 + lane * 16);               \
  }

#define TBODY(AH0, AL0, AH1, AL1, CHF, CLF, BX, MACC, LACC, Z0, Z1) {       \
    f4 _D0 = {Z0.x, Z0.y, Z0.z, Z0.w};  /* bias preloaded as C-in */        \
    _D0 = __builtin_amdgcn_mfma_f32_16x16x32_bf16(AH0, BX, _D0, 0, 0, 0);   \
    _D0 = __builtin_amdgcn_mfma_f32_16x16x32_bf16(AL0, BX, _D0, 0, 0, 0);   \
    f4 _D1 = {Z1.x, Z1.y, Z1.z, Z1.w};                                      \
    _D1 = __builtin_amdgcn_mfma_f32_16x16x32_bf16(AH1, BX, _D1, 0, 0, 0);   \
    _D1 = __builtin_amdgcn_mfma_f32_16x16x32_bf16(AL1, BX, _D1, 0, 0, 0);   \
    float _e0 = __builtin_amdgcn_exp2f(_D0[0]);                             \
    float _e1 = __builtin_amdgcn_exp2f(_D0[1]);                             \
    float _e2 = __builtin_amdgcn_exp2f(_D0[2]);                             \
    float _e3 = __builtin_amdgcn_exp2f(_D0[3]);                             \
    float _e4 = __builtin_amdgcn_exp2f(_D1[0]);                             \
    float _e5 = __builtin_amdgcn_exp2f(_D1[1]);                             \
    float _e6 = __builtin_amdgcn_exp2f(_D1[2]);                             \
    float _e7 = __builtin_amdgcn_exp2f(_D1[3]);                             \
    union { u32 u[4]; s8v v; } _Eh;                                         \
    _Eh.u[0] = cvtpk(_e0, _e1); _Eh.u[1] = cvtpk(_e2, _e3);                 \
    _Eh.u[2] = cvtpk(_e4, _e5); _Eh.u[3] = cvtpk(_e6, _e7);                 \
    MACC = __builtin_amdgcn_mfma_f32_16x16x32_bf16(CHF, _Eh.v, MACC, 0, 0, 0); \
    MACC = __builtin_amdgcn_mfma_f32_16x16x32_bf16(CLF, _Eh.v, MACC, 0, 0, 0); \
    LACC = __builtin_amdgcn_mfma_f32_16x16x32_bf16(ONES.v, _Eh.v, LACC, 0, 0, 0); \
  }

#define COMPUTE(P, c) {                                                     \
    const float* _zp = zL + (c) * 256 + s2 * 16 + g * 4;                    \
    float4 _z0 = *(const float4*)(_zp);                                     \
    float4 _z1 = *(const float4*)(_zp + 16);                                \
    TBODY(P##Ah0, P##Al0, P##Ah1, P##Al1, P##Ch, P##Cl, Bx0.v, macc0,       \
          lacc0, _z0, _z1);                                                 \
    TBODY(P##Ah0, P##Al0, P##Ah1, P##Al1, P##Ch, P##Cl, Bx1.v, macc1,       \
          lacc1, _z0, _z1);                                                 \
  }

  // prologue: z table for phase 0 (tt = 0)
  ZFILL(0.0f);
  __syncthreads();

  for (int step = 0; step < n_steps - 1; step++) {
#pragma unroll 1
    for (int mh = 0; mh < 2; mh++) {
      const float tt = (float)step * dt + (mh ? 0.5f * dt : 0.0f);
      const float* xsrc = mh ? xM : xT;
      // B-frags of mfma1 for both tiles: col=tok=q, k=g*8+j;
      // k<16 -> xh[d=k], k>=16 -> xl[d=k-16]. Group g covers d=(g&1)*8..+7.
      union { u32 u[4]; s8v v; } Bx0, Bx1;
#pragma unroll
      for (int T = 0; T < 2; T++) {
        const float* xp = xsrc + (T * 16 + q) * 16 + (g & 1) * 8;
        float4 a = *(const float4*)(xp);
        float4 b = *(const float4*)(xp + 4);
        u32 h0 = cvtpk(a.x, a.y), h1 = cvtpk(a.z, a.w);
        u32 h2 = cvtpk(b.x, b.y), h3 = cvtpk(b.z, b.w);
        u32 r0, r1, r2, r3;
        if (g < 2) {
          r0 = h0; r1 = h1; r2 = h2; r3 = h3;
        } else {
          r0 = cvtpk(a.x - lof(h0), a.y - hif(h0));
          r1 = cvtpk(a.z - lof(h1), a.w - hif(h1));
          r2 = cvtpk(b.x - lof(h2), b.y - hif(h2));
          r3 = cvtpk(b.z - lof(h3), b.w - hif(h3));
        }
        if (T == 0) { Bx0.u[0] = r0; Bx0.u[1] = r1; Bx0.u[2] = r2; Bx0.u[3] = r3; }
        else        { Bx1.u[0] = r0; Bx1.u[1] = r1; Bx1.u[2] = r2; Bx1.u[3] = r3; }
      }
      f4 macc0 = {0.f, 0.f, 0.f, 0.f}, macc1 = {0.f, 0.f, 0.f, 0.f};
      f4 lacc0 = {0.f, 0.f, 0.f, 0.f}, lacc1 = {0.f, 0.f, 0.f, 0.f};

      // chunk pipeline: this wave's 16 chunks {cpar, cpar+2, ...}, 1 ahead
      LOADF(a, cpar);
#pragma unroll 1
      for (int j = 0; j < 16; j += 2) {
        LOADF(b, cpar + 2 * (j + 1));
        COMPUTE(a, cpar + 2 * j);
        if (j + 2 < 16) LOADF(a, cpar + 2 * (j + 2));
        COMPUTE(b, cpar + 2 * (j + 1));
      }

      // partials: macc per lane; lsum complete per tok in lacc (any row reg)
      *(f4*)(redMp + ((wave * 2 + 0) * 64 + lane) * 16) = macc0;
      *(f4*)(redMp + ((wave * 2 + 1) * 64 + lane) * 16) = macc1;
      if (lane < 16) {
        redL[wave * 32 + lane] = lacc0[0];
        redL[wave * 32 + 16 + lane] = lacc1[0];
      }
      __syncthreads();
      // z table for the NEXT phase — overlaps the finalize serial window
      const float ttn = (mh == 0) ? (tt + 0.5f * dt) : ((float)(step + 1) * dt);
      ZFILL(ttn);
      if ((wave & 7) == 0) {  // waves 0 (tile0) and 8 (tile1) finalize
        const int T2 = wave >> 3;
        f4 m = {0.f, 0.f, 0.f, 0.f};
        float l2 = 0.f;
#pragma unroll
        for (int w = 0; w < 16; w++) {
          f4 o = *(const f4*)(redMp + ((w * 2 + T2) * 64 + lane) * 16);
          m += o;
          l2 += redL[w * 32 + T2 * 16 + q];
        }
        const float inv = 1.0f / fmaxf(l2, 1e-37f);
        const float inv1 = 1.0f / (1.0f - tt + 1e-10f);
        const float cf = (mh == 0) ? (0.5f * dt * inv1) : (dt * inv1);
        // lane owns (tok=q, d=g*4+j) of its tile: contiguous float4
        float4 xb = *(const float4*)(xT + (T2 * 16 + q) * 16 + g * 4);
        float4 xs = mh ? *(const float4*)(xM + (T2 * 16 + q) * 16 + g * 4) : xb;
        float4 xn;
        xn.x = fmaf(cf, m[0] * inv - xs.x, xb.x);
        xn.y = fmaf(cf, m[1] * inv - xs.y, xb.y);
        xn.z = fmaf(cf, m[2] * inv - xs.z, xb.z);
        xn.w = fmaf(cf, m[3] * inv - xs.w, xb.w);
        *(float4*)((mh ? xT : xM) + (T2 * 16 + q) * 16 + g * 4) = xn;
      }
      __syncthreads();
    }
  }

  // ---- outputs: x_final ----
  if (tid < 128)
    *(float4*)(out + tok0 * 16 + tid * 4) = *(const float4*)(xT + tid * 4);

  // ---- VQ argmin: d = ||c||^2 - 2 x.c; wave sweeps its 512 codes for all
  // 32 tokens (4 at a time, fully unrolled: no runtime-indexed arrays). ----
  const int wbase = wave * 512;
#pragma unroll 1
  for (int tg = 0; tg < 8; tg++) {
    float xr[4][16];
#pragma unroll
    for (int t = 0; t < 4; t++)
#pragma unroll
      for (int d4 = 0; d4 < 4; d4++)
        *(float4*)(&xr[t][d4 * 4]) = *(const float4*)(xT + (tg * 4 + t) * 16 + d4 * 4);
    float mv[4] = {3.402823466e38f, 3.402823466e38f, 3.402823466e38f, 3.402823466e38f};
    int mi[4] = {0, 0, 0, 0};
#pragma unroll 1
    for (int i = 0; i < 8; i++) {
      const int code = wbase + i * 64 + lane;
      float cr[16];
#pragma unroll
      for (int d4 = 0; d4 < 4; d4++)
        *(float4*)(&cr[d4 * 4]) = *(const float4*)(cb + code * 16 + d4 * 4);
      const float cc = CC2[code];
#pragma unroll
      for (int t = 0; t < 4; t++) {
        float dot = 0.f;
#pragma unroll
        for (int d = 0; d < 16; d++) dot = fmaf(xr[t][d], cr[d], dot);
        float dist = fmaf(-2.f, dot, cc);
        if (dist < mv[t]) { mv[t] = dist; mi[t] = code; }
      }
    }
#pragma unroll
    for (int t = 0; t < 4; t++) {
#pragma unroll
      for (int m = 1; m < 64; m <<= 1) {
        float ov = __shfl_xor(mv[t], m, 64);
        int oi = __shfl_xor(mi[t], m, 64);
        if (ov < mv[t] || (ov == mv[t] && oi < mi[t])) { mv[t] = ov; mi[t] = oi; }
      }
      if (lane == 0) {
        redV[wave * 32 + tg * 4 + t] = mv[t];
        redI[wave * 32 + tg * 4 + t] = mi[t];
      }
    }
  }
  __syncthreads();
  if (tid < 32) {
    float bv = redV[tid];
    int bi = redI[tid];
#pragma unroll
    for (int w = 1; w < 16; w++) {
      float ov = redV[w * 32 + tid];
      int oi = redI[w * 32 + tid];
      if (ov < bv || (ov == bv && oi < bi)) { bv = ov; bi = oi; }
    }
    out[NTOK * 16 + tok0 + tid] = (float)bi;
  }
}

extern "C" void kernel_launch(void* const* d_in, const int* in_sizes, int n_in,
                              void* d_out, int out_size, void* d_ws, size_t ws_size,
                              hipStream_t stream) {
  const float* x0 = (const float*)d_in[0];
  const float* cb = (const float*)d_in[1];
  const float* Wm = (const float*)d_in[2];
  const float* bm = (const float*)d_in[3];
  const float* tp = (const float*)d_in[4];
  const int* ns = (const int*)d_in[5];
  char* ws = (char*)d_ws;  // needs 1671168 B
  float* out = (float*)d_out;

  prep_kernel<<<512, 64, 0, stream>>>(cb, Wm, bm, tp, ws);
  flow_kernel<<<256, 1024, 0, stream>>>(x0, ws, cb, ns, out);
}

// Round 10
// 317.968 us; speedup vs baseline: 4.1913x; 1.1249x over previous
//
#include <hip/hip_runtime.h>

#define KS 1.8033688011112042f  // log2(e)/0.8
#define NTOK 8192
#define VV 8192
#define CHB 51200
#define WS_CC2B 1638400
#define WS_VQA  1671168   // (-2C) hi/lo frags, 32 chunks x 32768 B -> ws total 2719744

typedef float f4 __attribute__((ext_vector_type(4)));
typedef short s8v __attribute__((ext_vector_type(8)));
typedef unsigned int u32;
#define AS1 __attribute__((address_space(1)))
#define AS3 __attribute__((address_space(3)))

// RNE float->bf16, bit-ops (prep only — cold)
static __device__ __forceinline__ unsigned short f2bf(float f) {
  u32 u = __float_as_uint(f);
  return (unsigned short)((u + 0x7fffu + ((u >> 16) & 1u)) >> 16);
}
// HW packed conversion: D.lo16 = bf16(a), D.hi16 = bf16(b)
static __device__ __forceinline__ u32 cvtpk(float a, float b) {
  u32 r;
  asm("v_cvt_pk_bf16_f32 %0, %1, %2" : "=v"(r) : "v"(a), "v"(b));
  return r;
}
static __device__ __forceinline__ float lof(u32 h) {  // low bf16 as f32
  return __uint_as_float(h << 16);
}
static __device__ __forceinline__ float hif(u32 h) {  // high bf16 as f32
  return __uint_as_float(h & 0xffff0000u);
}

// ws layout: 32 chunks (256 codes), chunk-major, 51200 B each:
//   [0,16384) FragWh  [16384,32768) FragWl   (A of mfma1, W*KS hi/lo)
//   [32768,40960) FragCh  [40960,49152) FragCl (A of mfma2, K=32 pairing)
//   [49152,50176) BB fp32[256]  [50176,51200) BT fp32[256]
// CC2 fp32[8192] at WS_CC2B.
// VQA at WS_VQA: 32 chunks x {16 subtiles x 1024 B hi | +16384 lo} — (-2*C)
//   in the mfma1-A layout (row=code, k=g*8+j, value depends on d=k&15 only).
// ALL mfma are 16x16x32_bf16 (layout validated by the refcheck'd GEMM ladder).
__global__ __launch_bounds__(64) void prep_kernel(
    const float* __restrict__ cb, const float* __restrict__ Wm,
    const float* __restrict__ bm, const float* __restrict__ tp,
    char* __restrict__ ws) {
  const int ct = blockIdx.x;  // subtile 0..511 (16 codes)
  const int l = threadIdx.x;
  const int g = l >> 4, q = l & 15;
  const int c = ct >> 4, p = ct & 15;
  const int s = p >> 1, par = p & 1;
  char* chunk = ws + (size_t)c * CHB;
  {  // W fragment (A of mfma1): row=code=ct*16+q, k=g*8+j, d=k&15
    const int code = ct * 16 + q;
    unsigned short wh[8], wl[8];
#pragma unroll
    for (int j = 0; j < 8; j++) {
      int d = (g * 8 + j) & 15;
      float v = Wm[d * VV + code] * KS;
      unsigned short h = f2bf(v);
      wh[j] = h;
      wl[j] = f2bf(v - __uint_as_float((u32)h << 16));
    }
    uint4 hv, lv;
    hv.x = (u32)wh[0] | ((u32)wh[1] << 16); hv.y = (u32)wh[2] | ((u32)wh[3] << 16);
    hv.z = (u32)wh[4] | ((u32)wh[5] << 16); hv.w = (u32)wh[6] | ((u32)wh[7] << 16);
    lv.x = (u32)wl[0] | ((u32)wl[1] << 16); lv.y = (u32)wl[2] | ((u32)wl[3] << 16);
    lv.z = (u32)wl[4] | ((u32)wl[5] << 16); lv.w = (u32)wl[6] | ((u32)wl[7] << 16);
    *(uint4*)(chunk + p * 1024 + l * 16) = hv;
    *(uint4*)(chunk + 16384 + p * 1024 + l * 16) = lv;
  }
  {  // VQ A-fragment: (-2*C) in the same mfma1-A layout, hi/lo
    const int code = ct * 16 + q;
    unsigned short vh[8], vo[8];
#pragma unroll
    for (int j = 0; j < 8; j++) {
      int d = (g * 8 + j) & 15;
      float v = -2.0f * cb[code * 16 + d];
      unsigned short h = f2bf(v);
      vh[j] = h;
      vo[j] = f2bf(v - __uint_as_float((u32)h << 16));
    }
    uint4 hv, lv;
    hv.x = (u32)vh[0] | ((u32)vh[1] << 16); hv.y = (u32)vh[2] | ((u32)vh[3] << 16);
    hv.z = (u32)vh[4] | ((u32)vh[5] << 16); hv.w = (u32)vh[6] | ((u32)vh[7] << 16);
    lv.x = (u32)vo[0] | ((u32)vo[1] << 16); lv.y = (u32)vo[2] | ((u32)vo[3] << 16);
    lv.z = (u32)vo[4] | ((u32)vo[5] << 16); lv.w = (u32)vo[6] | ((u32)vo[7] << 16);
    char* vq = ws + WS_VQA + (size_t)c * 32768;
    *(uint4*)(vq + p * 1024 + l * 16) = hv;
    *(uint4*)(vq + 16384 + p * 1024 + l * 16) = lv;
  }
  {  // C pair-fragment (A of mfma2): block fills elems par*4+{0..3} of pair s
    unsigned short ch[4], cl_[4];
#pragma unroll
    for (int j = 0; j < 4; j++) {
      int code = ct * 16 + g * 4 + j;
      float v = cb[code * 16 + q];
      unsigned short h = f2bf(v);
      ch[j] = h;
      cl_[j] = f2bf(v - __uint_as_float((u32)h << 16));
    }
    uint2 hv = make_uint2((u32)ch[0] | ((u32)ch[1] << 16),
                          (u32)ch[2] | ((u32)ch[3] << 16));
    uint2 lv = make_uint2((u32)cl_[0] | ((u32)cl_[1] << 16),
                          (u32)cl_[2] | ((u32)cl_[3] << 16));
    *(uint2*)(chunk + 32768 + s * 1024 + l * 16 + par * 8) = hv;
    *(uint2*)(chunk + 40960 + s * 1024 + l * 16 + par * 8) = lv;
  }
  if (l < 16) {
    const int code = ct * 16 + l;
    *(float*)(chunk + 49152 + p * 64 + l * 4) = bm[code] * KS;
    *(float*)(chunk + 50176 + p * 64 + l * 4) = tp[code] * KS;
    float ss = 0.f;
#pragma unroll
    for (int d = 0; d < 16; d++) { float v = cb[code * 16 + d]; ss = fmaf(v, v, ss); }
    *(float*)(ws + WS_CC2B + code * 4) = ss;
  }
}

// R10 on top of R9: (1) VQ argmin MFMA-ized — dist = cc - 2x.c via 2 hi/lo
// mfma1-style MFMAs per subtile, D initialized with cc (precision 2^-17,
// argmin-safe: 25x under the surviving R9 perturbation). (2) ZFILL bank-
// conflict fix (16-B lane stride). (3) next-phase chunk-0 LOADF hoisted after
// barrier 1 so its L2 latency hides under the finalize serial window.
// Rest identical to R9. CRITICAL (rule #20): named regs, compile-time indices.
__global__ __launch_bounds__(1024, 4) void flow_kernel(
    const float* __restrict__ x0, const char* __restrict__ ws,
    const float* __restrict__ cb, const int* __restrict__ nsp,
    float* __restrict__ out) {
  __shared__ __align__(16) char smem[141312];
  char* biasL = smem;                       // [32 chunks][2048 B] BB|BT
  float* xT = (float*)(smem + 65536);       // [32][16] base state
  float* xM = (float*)(smem + 67584);       // [32][16] midpoint state
  char* redMp = smem + 69632;               // [16 waves][2 tiles][64] f4 (32 KB)
  float* redL = (float*)(smem + 102400);    // [16][32] lsum partials
  float* redV = (float*)(smem + 104448);    // [16][32] VQ min val
  int* redI = (int*)(smem + 106496);        // [16][32] VQ min idx
  float* zL = (float*)(smem + 108544);      // [32 chunks][256] z table (32 KB)
  const float* CC2 = (const float*)(ws + WS_CC2B);

  const int tid = threadIdx.x;
  const int lane = tid & 63, wave = tid >> 6;  // 16 waves
  const int s = wave & 7, cpar = wave >> 3;    // pair id, chunk parity
  const int s2 = s * 2;
  const int g = lane >> 4, q = lane & 15;
  const int tok0 = blockIdx.x * 32;

  if (tid < 128)
    *(float4*)(xT + tid * 4) = *(const float4*)(x0 + tok0 * 16 + tid * 4);
  // biases -> LDS once (wave-uniform dst base + lane*16: valid global_load_lds)
#pragma unroll
  for (int sw = 0; sw < 4; sw++) {
    const int c = sw * 8 + (tid >> 7);
    const int off = (tid & 127) * 16;
    __builtin_amdgcn_global_load_lds(
        (const AS1 u32*)(ws + (size_t)c * CHB + 49152 + off),
        (AS3 u32*)(biasL + c * 2048 + off), 16, 0, 0);
  }
  __syncthreads();

  const int n_steps = *nsp;
  const float dt = 1.0f / (float)(n_steps - 1);

  // ones A-fragment for the lsum MFMA
  union { u32 u[4]; s8v v; } ONES;
  ONES.u[0] = ONES.u[1] = ONES.u[2] = ONES.u[3] = 0x3f803f80u;

  // named double-buffered fragment registers (NO arrays — rule #20)
  s8v aAh0, aAl0, aAh1, aAl1, aCh, aCl;
  s8v bAh0, bAl0, bAh1, bAl1, bCh, bCl;

// conflict-light ZFILL: lanes write 16-B-contiguous (2 passes of 128 floats)
#define ZFILL(TT) {                                                         \
    const int _c = tid >> 5;                                                \
    const int _t = tid & 31;                                                \
    const char* _bp = biasL + _c * 2048;                                    \
    float4 _b0 = *(const float4*)(_bp + _t * 16);                           \
    float4 _t0 = *(const float4*)(_bp + 1024 + _t * 16);                    \
    float4 _b1 = *(const float4*)(_bp + 512 + _t * 16);                     \
    float4 _t1 = *(const float4*)(_bp + 1536 + _t * 16);                    \
    float4 _za, _zb;                                                        \
    _za.x = fmaf(TT, _t0.x, _b0.x); _za.y = fmaf(TT, _t0.y, _b0.y);         \
    _za.z = fmaf(TT, _t0.z, _b0.z); _za.w = fmaf(TT, _t0.w, _b0.w);         \
    _zb.x = fmaf(TT, _t1.x, _b1.x); _zb.y = fmaf(TT, _t1.y, _b1.y);         \
    _zb.z = fmaf(TT, _t1.z, _b1.z); _zb.w = fmaf(TT, _t1.w, _b1.w);         \
    *(float4*)(zL + _c * 256 + _t * 4) = _za;                               \
    *(float4*)(zL + _c * 256 + 128 + _t * 4) = _zb;                         \
  }

#define LOADF(P, c) {                                                       \
    const char* _p = ws + (size_t)(c) * CHB;                                \
    P##Ah0 = *(const s8v*)(_p + s2 * 1024 + lane * 16);                     \
    P##Al0 = *(const s8v*)(_p + 16384 + s2 * 1024 + lane * 16);             \
    P##Ah1 = *(const s8v*)(_p + (s2 + 1) * 1024 + lane * 16);               \
    P##Al1 = *(const s8v*)(_p + 16384 + (s2 + 1) * 1024 + lane * 16);       \
    P##Ch = *(const s8v*)(_p + 32768 + s * 1024 + lane * 16);               \
    P##Cl = *(const s8v*)(_p + 40960 + s * 1024 + lane * 16);               \
  }

#define TBODY(AH0, AL0, AH1, AL1, CHF, CLF, BX, MACC, LACC, Z0, Z1) {       \
    f4 _D0 = {Z0.x, Z0.y, Z0.z, Z0.w};  /* bias preloaded as C-in */        \
    _D0 = __builtin_amdgcn_mfma_f32_16x16x32_bf16(AH0, BX, _D0, 0, 0, 0);   \
    _D0 = __builtin_amdgcn_mfma_f32_16x16x32_bf16(AL0, BX, _D0, 0, 0, 0);   \
    f4 _D1 = {Z1.x, Z1.y, Z1.z, Z1.w};                                      \
    _D1 = __builtin_amdgcn_mfma_f32_16x16x32_bf16(AH1, BX, _D1, 0, 0, 0);   \
    _D1 = __builtin_amdgcn_mfma_f32_16x16x32_bf16(AL1, BX, _D1, 0, 0, 0);   \
    float _e0 = __builtin_amdgcn_exp2f(_D0[0]);                             \
    float _e1 = __builtin_amdgcn_exp2f(_D0[1]);                             \
    float _e2 = __builtin_amdgcn_exp2f(_D0[2]);                             \
    float _e3 = __builtin_amdgcn_exp2f(_D0[3]);                             \
    float _e4 = __builtin_amdgcn_exp2f(_D1[0]);                             \
    float _e5 = __builtin_amdgcn_exp2f(_D1[1]);                             \
    float _e6 = __builtin_amdgcn_exp2f(_D1[2]);                             \
    float _e7 = __builtin_amdgcn_exp2f(_D1[3]);                             \
    union { u32 u[4]; s8v v; } _Eh;                                         \
    _Eh.u[0] = cvtpk(_e0, _e1); _Eh.u[1] = cvtpk(_e2, _e3);                 \
    _Eh.u[2] = cvtpk(_e4, _e5); _Eh.u[3] = cvtpk(_e6, _e7);                 \
    MACC = __builtin_amdgcn_mfma_f32_16x16x32_bf16(CHF, _Eh.v, MACC, 0, 0, 0); \
    MACC = __builtin_amdgcn_mfma_f32_16x16x32_bf16(CLF, _Eh.v, MACC, 0, 0, 0); \
    LACC = __builtin_amdgcn_mfma_f32_16x16x32_bf16(ONES.v, _Eh.v, LACC, 0, 0, 0); \
  }

#define COMPUTE(P, c) {                                                     \
    const float* _zp = zL + (c) * 256 + s2 * 16 + g * 4;                    \
    float4 _z0 = *(const float4*)(_zp);                                     \
    float4 _z1 = *(const float4*)(_zp + 16);                                \
    TBODY(P##Ah0, P##Al0, P##Ah1, P##Al1, P##Ch, P##Cl, Bx0.v, macc0,       \
          lacc0, _z0, _z1);                                                 \
    TBODY(P##Ah0, P##Al0, P##Ah1, P##Al1, P##Ch, P##Cl, Bx1.v, macc1,       \
          lacc1, _z0, _z1);                                                 \
  }

  // prologue: z table for phase 0 (tt = 0) + first chunk prefetch
  ZFILL(0.0f);
  LOADF(a, cpar);
  __syncthreads();

  for (int step = 0; step < n_steps - 1; step++) {
#pragma unroll 1
    for (int mh = 0; mh < 2; mh++) {
      const float tt = (float)step * dt + (mh ? 0.5f * dt : 0.0f);
      const float* xsrc = mh ? xM : xT;
      // B-frags of mfma1 for both tiles: col=tok=q, k=g*8+j;
      // k<16 -> xh[d=k], k>=16 -> xl[d=k-16]. Group g covers d=(g&1)*8..+7.
      union { u32 u[4]; s8v v; } Bx0, Bx1;
#pragma unroll
      for (int T = 0; T < 2; T++) {
        const float* xp = xsrc + (T * 16 + q) * 16 + (g & 1) * 8;
        float4 a = *(const float4*)(xp);
        float4 b = *(const float4*)(xp + 4);
        u32 h0 = cvtpk(a.x, a.y), h1 = cvtpk(a.z, a.w);
        u32 h2 = cvtpk(b.x, b.y), h3 = cvtpk(b.z, b.w);
        u32 r0, r1, r2, r3;
        if (g < 2) {
          r0 = h0; r1 = h1; r2 = h2; r3 = h3;
        } else {
          r0 = cvtpk(a.x - lof(h0), a.y - hif(h0));
          r1 = cvtpk(a.z - lof(h1), a.w - hif(h1));
          r2 = cvtpk(b.x - lof(h2), b.y - hif(h2));
          r3 = cvtpk(b.z - lof(h3), b.w - hif(h3));
        }
        if (T == 0) { Bx0.u[0] = r0; Bx0.u[1] = r1; Bx0.u[2] = r2; Bx0.u[3] = r3; }
        else        { Bx1.u[0] = r0; Bx1.u[1] = r1; Bx1.u[2] = r2; Bx1.u[3] = r3; }
      }
      f4 macc0 = {0.f, 0.f, 0.f, 0.f}, macc1 = {0.f, 0.f, 0.f, 0.f};
      f4 lacc0 = {0.f, 0.f, 0.f, 0.f}, lacc1 = {0.f, 0.f, 0.f, 0.f};

      // chunk pipeline: this wave's 16 chunks {cpar, cpar+2, ...}, 1 ahead
      // (a-regs preloaded with chunk cpar by prologue / previous phase tail)
#pragma unroll 1
      for (int j = 0; j < 16; j += 2) {
        LOADF(b, cpar + 2 * (j + 1));
        COMPUTE(a, cpar + 2 * j);
        if (j + 2 < 16) LOADF(a, cpar + 2 * (j + 2));
        COMPUTE(b, cpar + 2 * (j + 1));
      }

      // partials: macc per lane; lsum complete per tok in lacc (any row reg)
      *(f4*)(redMp + ((wave * 2 + 0) * 64 + lane) * 16) = macc0;
      *(f4*)(redMp + ((wave * 2 + 1) * 64 + lane) * 16) = macc1;
      if (lane < 16) {
        redL[wave * 32 + lane] = lacc0[0];
        redL[wave * 32 + 16 + lane] = lacc1[0];
      }
      __syncthreads();
      // prefetch next phase's first chunk — L2 latency hides under finalize
      LOADF(a, cpar);
      // z table for the NEXT phase — overlaps the finalize serial window
      const float ttn = (mh == 0) ? (tt + 0.5f * dt) : ((float)(step + 1) * dt);
      ZFILL(ttn);
      if ((wave & 7) == 0) {  // waves 0 (tile0) and 8 (tile1) finalize
        const int T2 = wave >> 3;
        f4 m = {0.f, 0.f, 0.f, 0.f};
        float l2 = 0.f;
#pragma unroll
        for (int w = 0; w < 16; w++) {
          f4 o = *(const f4*)(redMp + ((w * 2 + T2) * 64 + lane) * 16);
          m += o;
          l2 += redL[w * 32 + T2 * 16 + q];
        }
        const float inv = 1.0f / fmaxf(l2, 1e-37f);
        const float inv1 = 1.0f / (1.0f - tt + 1e-10f);
        const float cf = (mh == 0) ? (0.5f * dt * inv1) : (dt * inv1);
        // lane owns (tok=q, d=g*4+j) of its tile: contiguous float4
        float4 xb = *(const float4*)(xT + (T2 * 16 + q) * 16 + g * 4);
        float4 xs = mh ? *(const float4*)(xM + (T2 * 16 + q) * 16 + g * 4) : xb;
        float4 xn;
        xn.x = fmaf(cf, m[0] * inv - xs.x, xb.x);
        xn.y = fmaf(cf, m[1] * inv - xs.y, xb.y);
        xn.z = fmaf(cf, m[2] * inv - xs.z, xb.z);
        xn.w = fmaf(cf, m[3] * inv - xs.w, xb.w);
        *(float4*)((mh ? xT : xM) + (T2 * 16 + q) * 16 + g * 4) = xn;
      }
      __syncthreads();
    }
  }

  // ---- outputs: x_final ----
  if (tid < 128)
    *(float4*)(out + tok0 * 16 + tid * 4) = *(const float4*)(xT + tid * 4);

  // ---- VQ argmin via MFMA: dist = cc - 2 x.c, hi/lo dots (2^-17) ----
  union { u32 u[4]; s8v v; } Vx0, Vx1;
#pragma unroll
  for (int T = 0; T < 2; T++) {
    const float* xp = xT + (T * 16 + q) * 16 + (g & 1) * 8;
    float4 a = *(const float4*)(xp);
    float4 b = *(const float4*)(xp + 4);
    u32 h0 = cvtpk(a.x, a.y), h1 = cvtpk(a.z, a.w);
    u32 h2 = cvtpk(b.x, b.y), h3 = cvtpk(b.z, b.w);
    u32 r0, r1, r2, r3;
    if (g < 2) {
      r0 = h0; r1 = h1; r2 = h2; r3 = h3;
    } else {
      r0 = cvtpk(a.x - lof(h0), a.y - hif(h0));
      r1 = cvtpk(a.z - lof(h1), a.w - hif(h1));
      r2 = cvtpk(b.x - lof(h2), b.y - hif(h2));
      r3 = cvtpk(b.z - lof(h3), b.w - hif(h3));
    }
    if (T == 0) { Vx0.u[0] = r0; Vx0.u[1] = r1; Vx0.u[2] = r2; Vx0.u[3] = r3; }
    else        { Vx1.u[0] = r0; Vx1.u[1] = r1; Vx1.u[2] = r2; Vx1.u[3] = r3; }
  }
  float mv0 = 3.402823466e38f, mv1 = 3.402823466e38f;
  int mi0 = 0, mi1 = 0;
  s8v pAh0, pAl0, pAh1, pAl1;
  s8v qAh0, qAl0, qAh1, qAl1;
  float4 pC0, pC1, qC0, qC1;

#define VQLOAD(P, c) {                                                      \
    const char* _a = ws + WS_VQA + (size_t)(c) * 32768;                     \
    P##Ah0 = *(const s8v*)(_a + s2 * 1024 + lane * 16);                     \
    P##Al0 = *(const s8v*)(_a + 16384 + s2 * 1024 + lane * 16);             \
    P##Ah1 = *(const s8v*)(_a + (s2 + 1) * 1024 + lane * 16);               \
    P##Al1 = *(const s8v*)(_a + 16384 + (s2 + 1) * 1024 + lane * 16);       \
    P##C0 = *(const float4*)(CC2 + (c) * 256 + s2 * 16 + (lane >> 4) * 4);  \
    P##C1 = *(const float4*)(CC2 + (c) * 256 + (s2 + 1) * 16 + (lane >> 4) * 4); \
  }

#define VQMIN(MV, MI, DV, IDX) { float _d = (DV); if (_d < MV) { MV = _d; MI = (IDX); } }

#define VQTILE(P, VX, MV, MI, c) {                                          \
    const int _b0 = (c) * 256 + s2 * 16 + (lane >> 4) * 4;                  \
    const int _b1 = _b0 + 16;                                               \
    f4 _E0 = {P##C0.x, P##C0.y, P##C0.z, P##C0.w};                          \
    _E0 = __builtin_amdgcn_mfma_f32_16x16x32_bf16(P##Ah0, VX, _E0, 0, 0, 0);\
    _E0 = __builtin_amdgcn_mfma_f32_16x16x32_bf16(P##Al0, VX, _E0, 0, 0, 0);\
    f4 _E1 = {P##C1.x, P##C1.y, P##C1.z, P##C1.w};                          \
    _E1 = __builtin_amdgcn_mfma_f32_16x16x32_bf16(P##Ah1, VX, _E1, 0, 0, 0);\
    _E1 = __builtin_amdgcn_mfma_f32_16x16x32_bf16(P##Al1, VX, _E1, 0, 0, 0);\
    VQMIN(MV, MI, _E0[0], _b0 + 0); VQMIN(MV, MI, _E0[1], _b0 + 1);         \
    VQMIN(MV, MI, _E0[2], _b0 + 2); VQMIN(MV, MI, _E0[3], _b0 + 3);         \
    VQMIN(MV, MI, _E1[0], _b1 + 0); VQMIN(MV, MI, _E1[1], _b1 + 1);         \
    VQMIN(MV, MI, _E1[2], _b1 + 2); VQMIN(MV, MI, _E1[3], _b1 + 3);         \
  }

#define VQSTEP(P, c) { VQTILE(P, Vx0.v, mv0, mi0, c) VQTILE(P, Vx1.v, mv1, mi1, c) }

  VQLOAD(p, cpar);
#pragma unroll 1
  for (int i = 0; i < 16; i += 2) {
    VQLOAD(q, cpar + 2 * (i + 1));
    VQSTEP(p, cpar + 2 * i);
    if (i + 2 < 16) VQLOAD(p, cpar + 2 * (i + 2));
    VQSTEP(q, cpar + 2 * (i + 1));
  }
  // cross-lane argmin over the 4 lanes sharing tok = lane&15 (rows)
#pragma unroll
  for (int m = 16; m < 64; m <<= 1) {
    float ov0 = __shfl_xor(mv0, m, 64); int oi0 = __shfl_xor(mi0, m, 64);
    if (ov0 < mv0 || (ov0 == mv0 && oi0 < mi0)) { mv0 = ov0; mi0 = oi0; }
    float ov1 = __shfl_xor(mv1, m, 64); int oi1 = __shfl_xor(mi1, m, 64);
    if (ov1 < mv1 || (ov1 == mv1 && oi1 < mi1)) { mv1 = ov1; mi1 = oi1; }
  }
  if (lane < 16) {
    redV[wave * 32 + lane] = mv0; redI[wave * 32 + lane] = mi0;
    redV[wave * 32 + 16 + lane] = mv1; redI[wave * 32 + 16 + lane] = mi1;
  }
  __syncthreads();
  if (tid < 32) {
    float bv = redV[tid];
    int bi = redI[tid];
#pragma unroll
    for (int w = 1; w < 16; w++) {
      float ov = redV[w * 32 + tid];
      int oi = redI[w * 32 + tid];
      if (ov < bv || (ov == bv && oi < bi)) { bv = ov; bi = oi; }
    }
    out[NTOK * 16 + tok0 + tid] = (float)bi;
  }
}

extern "C" void kernel_launch(void* const* d_in, const int* in_sizes, int n_in,
                              void* d_out, int out_size, void* d_ws, size_t ws_size,
                              hipStream_t stream) {
  const float* x0 = (const float*)d_in[0];
  const float* cb = (const float*)d_in[1];
  const float* Wm = (const float*)d_in[2];
  const float* bm = (const float*)d_in[3];
  const float* tp = (const float*)d_in[4];
  const int* ns = (const int*)d_in[5];
  char* ws = (char*)d_ws;  // needs 2719744 B
  float* out = (float*)d_out;

  prep_kernel<<<512, 64, 0, stream>>>(cb, Wm, bm, tp, ws);
  flow_kernel<<<256, 1024, 0, stream>>>(x0, ws, cb, ns, out);
}

// Round 12
// 312.911 us; speedup vs baseline: 4.2590x; 1.0162x over previous
//
#include <hip/hip_runtime.h>

#define KS 1.8033688011112042f  // log2(e)/0.8
#define ZSH 8.0f                // constant exponent shift: E *= 2^-8 (cancels in mu)
#define NTOK 8192
#define VV 8192
#define CHB 26624               // f16 chunk: W 16K + C 8K + BB 1K + BT 1K
#define WS_CC2B 851968
#define WS_VQA  884736          // (-2C) bf16 hi/lo frags, 32 x 32768 -> ws 1933312 B

typedef float f4 __attribute__((ext_vector_type(4)));
typedef short s8v __attribute__((ext_vector_type(8)));
typedef _Float16 h8v __attribute__((ext_vector_type(8)));
typedef unsigned int u32;
#define AS1 __attribute__((address_space(1)))
#define AS3 __attribute__((address_space(3)))

// RNE float->bf16, bit-ops (prep + VQ path)
static __device__ __forceinline__ unsigned short f2bf(float f) {
  u32 u = __float_as_uint(f);
  return (unsigned short)((u + 0x7fffu + ((u >> 16) & 1u)) >> 16);
}
static __device__ __forceinline__ unsigned short f2h(float f) {  // RNE f32->f16
  _Float16 h = (_Float16)f;
  return __builtin_bit_cast(unsigned short, h);
}
// f16 pack via PLAIN CASTS (no inline asm — compiler-correct by construction)
static __device__ __forceinline__ u32 pkh(float a, float b) {
  return (u32)f2h(a) | ((u32)f2h(b) << 16);
}
static __device__ __forceinline__ float h2f(float a) {  // RNE f16 of a, as f32
  return (float)(_Float16)a;
}
// bf16 pack for the VQ path (proven since R3)
static __device__ __forceinline__ u32 cvtpk(float a, float b) {
  u32 r;
  asm("v_cvt_pk_bf16_f32 %0, %1, %2" : "=v"(r) : "v"(a), "v"(b));
  return r;
}
static __device__ __forceinline__ float lof(u32 h) {  // low bf16 as f32
  return __uint_as_float(h << 16);
}
static __device__ __forceinline__ float hif(u32 h) {  // high bf16 as f32
  return __uint_as_float(h & 0xffff0000u);
}

// ws layout (f16 flow path): 32 chunks x 26624 B:
//   [0,16384)     Wf16: 16 subtiles x 64 lanes x 8 f16 (A of mfma1, W*KS, RNE)
//   [16384,24576) Cf16: 8 PAIRS x 64 lanes x 8 f16 (A of mfma2, K=32 pairing)
//   [24576,25600) BB fp32[256] (bm*KS - 8)   [25600,26624) BT fp32[256]
// CC2 fp32[8192] at WS_CC2B; VQA ((-2C) bf16 hi/lo, mfma1-A layout) at WS_VQA.
// f16 16x16x32 MFMA layout: same family as bf16 (A/B exercised by m121-128
// all-dtype probes vs reference; C/D dtype-independent, HW-verified).
// Exponent shift -8 + D-clamp at 15 keeps E in f16 range ALWAYS (structural
// NaN-proofing: mu = weighted avg stays bounded even under a value bug).
__global__ __launch_bounds__(64) void prep_kernel(
    const float* __restrict__ cb, const float* __restrict__ Wm,
    const float* __restrict__ bm, const float* __restrict__ tp,
    char* __restrict__ ws) {
  const int ct = blockIdx.x;  // subtile 0..511 (16 codes)
  const int l = threadIdx.x;
  const int g = l >> 4, q = l & 15;
  const int c = ct >> 4, p = ct & 15;
  const int s = p >> 1, par = p & 1;
  char* chunk = ws + (size_t)c * CHB;
  {  // W fragment (A of mfma1): row=code=ct*16+q, k=g*8+j, d=k&15, f16 RNE
    const int code = ct * 16 + q;
    unsigned short wh[8];
#pragma unroll
    for (int j = 0; j < 8; j++) {
      int d = (g * 8 + j) & 15;
      wh[j] = f2h(Wm[d * VV + code] * KS);
    }
    uint4 hv;
    hv.x = (u32)wh[0] | ((u32)wh[1] << 16); hv.y = (u32)wh[2] | ((u32)wh[3] << 16);
    hv.z = (u32)wh[4] | ((u32)wh[5] << 16); hv.w = (u32)wh[6] | ((u32)wh[7] << 16);
    *(uint4*)(chunk + p * 1024 + l * 16) = hv;
  }
  {  // VQ A-fragment: (-2*C) bf16 hi/lo in mfma1-A layout (unchanged, proven)
    const int code = ct * 16 + q;
    unsigned short vh[8], vo[8];
#pragma unroll
    for (int j = 0; j < 8; j++) {
      int d = (g * 8 + j) & 15;
      float v = -2.0f * cb[code * 16 + d];
      unsigned short h = f2bf(v);
      vh[j] = h;
      vo[j] = f2bf(v - __uint_as_float((u32)h << 16));
    }
    uint4 hv, lv;
    hv.x = (u32)vh[0] | ((u32)vh[1] << 16); hv.y = (u32)vh[2] | ((u32)vh[3] << 16);
    hv.z = (u32)vh[4] | ((u32)vh[5] << 16); hv.w = (u32)vh[6] | ((u32)vh[7] << 16);
    lv.x = (u32)vo[0] | ((u32)vo[1] << 16); lv.y = (u32)vo[2] | ((u32)vo[3] << 16);
    lv.z = (u32)vo[4] | ((u32)vo[5] << 16); lv.w = (u32)vo[6] | ((u32)vo[7] << 16);
    char* vq = ws + WS_VQA + (size_t)c * 32768;
    *(uint4*)(vq + p * 1024 + l * 16) = hv;
    *(uint4*)(vq + 16384 + p * 1024 + l * 16) = lv;
  }
  {  // C pair-fragment (A of mfma2), f16 RNE: elems par*4+{0..3} of pair s
    unsigned short ch[4];
#pragma unroll
    for (int j = 0; j < 4; j++) {
      int code = ct * 16 + g * 4 + j;
      ch[j] = f2h(cb[code * 16 + q]);
    }
    uint2 hv = make_uint2((u32)ch[0] | ((u32)ch[1] << 16),
                          (u32)ch[2] | ((u32)ch[3] << 16));
    *(uint2*)(chunk + 16384 + s * 1024 + l * 16 + par * 8) = hv;
  }
  if (l < 16) {
    const int code = ct * 16 + l;
    *(float*)(chunk + 24576 + p * 64 + l * 4) = bm[code] * KS - ZSH;
    *(float*)(chunk + 25600 + p * 64 + l * 4) = tp[code] * KS;
    float ss = 0.f;
#pragma unroll
    for (int d = 0; d < 16; d++) { float v = cb[code * 16 + d]; ss = fmaf(v, v, ss); }
    *(float*)(ws + WS_CC2B + code * 4) = ss;
  }
}

// R12 = R11 f16 path, de-risked by construction:
//  - NO f16 inline asm: all f32->f16 via (_Float16) casts (pkh), RNE.
//  - fminf(D,15) before exp2: E <= 2^15 < f16-max ALWAYS -> no inf -> mu
//    bounded (weighted avg) -> integrator cannot diverge; bug => finite diag.
// Structure identical to R10/R11: zL table, direct L2->VGPR streaming, wave-
// private chunks, named double-buffered regs (rule #20), 2 barriers/phase,
// prefetch in finalize window, VQ argmin via bf16 MFMA (bit-identical to R10).
__global__ __launch_bounds__(1024, 4) void flow_kernel(
    const float* __restrict__ x0, const char* __restrict__ ws,
    const float* __restrict__ cb, const int* __restrict__ nsp,
    float* __restrict__ out) {
  __shared__ __align__(16) char smem[141312];
  char* biasL = smem;                       // [32 chunks][2048 B] BB|BT
  float* xT = (float*)(smem + 65536);       // [32][16] base state
  float* xM = (float*)(smem + 67584);       // [32][16] midpoint state
  char* redMp = smem + 69632;               // [16 waves][2 tiles][64] f4 (32 KB)
  float* redL = (float*)(smem + 102400);    // [16][32] lsum partials
  float* redV = (float*)(smem + 104448);    // [16][32] VQ min val
  int* redI = (int*)(smem + 106496);        // [16][32] VQ min idx
  float* zL = (float*)(smem + 108544);      // [32 chunks][256] z table (32 KB)
  const float* CC2 = (const float*)(ws + WS_CC2B);

  const int tid = threadIdx.x;
  const int lane = tid & 63, wave = tid >> 6;  // 16 waves
  const int s = wave & 7, cpar = wave >> 3;    // pair id, chunk parity
  const int s2 = s * 2;
  const int g = lane >> 4, q = lane & 15;
  const int tok0 = blockIdx.x * 32;

  if (tid < 128)
    *(float4*)(xT + tid * 4) = *(const float4*)(x0 + tok0 * 16 + tid * 4);
  // biases -> LDS once (wave-uniform dst base + lane*16: valid global_load_lds)
#pragma unroll
  for (int sw = 0; sw < 4; sw++) {
    const int c = sw * 8 + (tid >> 7);
    const int off = (tid & 127) * 16;
    __builtin_amdgcn_global_load_lds(
        (const AS1 u32*)(ws + (size_t)c * CHB + 24576 + off),
        (AS3 u32*)(biasL + c * 2048 + off), 16, 0, 0);
  }
  __syncthreads();

  const int n_steps = *nsp;
  const float dt = 1.0f / (float)(n_steps - 1);

  // ones A-fragment (f16 1.0 pairs) for the lsum MFMA
  union { u32 u[4]; h8v h; } ONESH;
  ONESH.u[0] = ONESH.u[1] = ONESH.u[2] = ONESH.u[3] = 0x3c003c00u;

  // named double-buffered fragment registers (NO arrays — rule #20)
  h8v aW0, aW1, aCf;
  h8v bW0, bW1, bCf;

// conflict-light ZFILL: lanes write 16-B-contiguous (2 passes of 128 floats)
#define ZFILL(TT) {                                                         \
    const int _c = tid >> 5;                                                \
    const int _t = tid & 31;                                                \
    const char* _bp = biasL + _c * 2048;                                    \
    float4 _b0 = *(const float4*)(_bp + _t * 16);                           \
    float4 _t0 = *(const float4*)(_bp + 1024 + _t * 16);                    \
    float4 _b1 = *(const float4*)(_bp + 512 + _t * 16);                     \
    float4 _t1 = *(const float4*)(_bp + 1536 + _t * 16);                    \
    float4 _za, _zb;                                                        \
    _za.x = fmaf(TT, _t0.x, _b0.x); _za.y = fmaf(TT, _t0.y, _b0.y);         \
    _za.z = fmaf(TT, _t0.z, _b0.z); _za.w = fmaf(TT, _t0.w, _b0.w);         \
    _zb.x = fmaf(TT, _t1.x, _b1.x); _zb.y = fmaf(TT, _t1.y, _b1.y);         \
    _zb.z = fmaf(TT, _t1.z, _b1.z); _zb.w = fmaf(TT, _t1.w, _b1.w);         \
    *(float4*)(zL + _c * 256 + _t * 4) = _za;                               \
    *(float4*)(zL + _c * 256 + 128 + _t * 4) = _zb;                         \
  }

#define LOADF(P, c) {                                                       \
    const char* _p = ws + (size_t)(c) * CHB;                                \
    P##W0 = *(const h8v*)(_p + s2 * 1024 + lane * 16);                      \
    P##W1 = *(const h8v*)(_p + (s2 + 1) * 1024 + lane * 16);                \
    P##Cf = *(const h8v*)(_p + 16384 + s * 1024 + lane * 16);               \
  }

#define TBODY(W0F, W1F, CFF, BX, MACC, LACC, Z0, Z1) {                      \
    f4 _D0 = {Z0.x, Z0.y, Z0.z, Z0.w};  /* bias (incl -8 shift) as C-in */  \
    _D0 = __builtin_amdgcn_mfma_f32_16x16x32_f16(W0F, BX, _D0, 0, 0, 0);    \
    f4 _D1 = {Z1.x, Z1.y, Z1.z, Z1.w};                                      \
    _D1 = __builtin_amdgcn_mfma_f32_16x16x32_f16(W1F, BX, _D1, 0, 0, 0);    \
    float _e0 = __builtin_amdgcn_exp2f(fminf(_D0[0], 15.f));                \
    float _e1 = __builtin_amdgcn_exp2f(fminf(_D0[1], 15.f));                \
    float _e2 = __builtin_amdgcn_exp2f(fminf(_D0[2], 15.f));                \
    float _e3 = __builtin_amdgcn_exp2f(fminf(_D0[3], 15.f));                \
    float _e4 = __builtin_amdgcn_exp2f(fminf(_D1[0], 15.f));                \
    float _e5 = __builtin_amdgcn_exp2f(fminf(_D1[1], 15.f));                \
    float _e6 = __builtin_amdgcn_exp2f(fminf(_D1[2], 15.f));                \
    float _e7 = __builtin_amdgcn_exp2f(fminf(_D1[3], 15.f));                \
    union { u32 u[4]; h8v h; } _Eh;                                         \
    _Eh.u[0] = pkh(_e0, _e1); _Eh.u[1] = pkh(_e2, _e3);                     \
    _Eh.u[2] = pkh(_e4, _e5); _Eh.u[3] = pkh(_e6, _e7);                     \
    MACC = __builtin_amdgcn_mfma_f32_16x16x32_f16(CFF, _Eh.h, MACC, 0, 0, 0); \
    LACC = __builtin_amdgcn_mfma_f32_16x16x32_f16(ONESH.h, _Eh.h, LACC, 0, 0, 0); \
  }

#define COMPUTE(P, c) {                                                     \
    const float* _zp = zL + (c) * 256 + s2 * 16 + g * 4;                    \
    float4 _z0 = *(const float4*)(_zp);                                     \
    float4 _z1 = *(const float4*)(_zp + 16);                                \
    TBODY(P##W0, P##W1, P##Cf, Bx0.h, macc0, lacc0, _z0, _z1);              \
    TBODY(P##W0, P##W1, P##Cf, Bx1.h, macc1, lacc1, _z0, _z1);              \
  }

  // prologue: z table for phase 0 (tt = 0) + first chunk prefetch
  ZFILL(0.0f);
  LOADF(a, cpar);
  __syncthreads();

  for (int step = 0; step < n_steps - 1; step++) {
#pragma unroll 1
    for (int mh = 0; mh < 2; mh++) {
      const float tt = (float)step * dt + (mh ? 0.5f * dt : 0.0f);
      const float* xsrc = mh ? xM : xT;
      // B-frags of mfma1: col=tok=q, k=g*8+j; k<16 -> xh[d=k] (f16 RNE),
      // k>=16 -> xl[d=k-16] (residual vs the same RNE). g covers d=(g&1)*8..+7.
      union { u32 u[4]; h8v h; } Bx0, Bx1;
#pragma unroll
      for (int T = 0; T < 2; T++) {
        const float* xp = xsrc + (T * 16 + q) * 16 + (g & 1) * 8;
        float4 a = *(const float4*)(xp);
        float4 b = *(const float4*)(xp + 4);
        u32 r0, r1, r2, r3;
        if (g < 2) {
          r0 = pkh(a.x, a.y); r1 = pkh(a.z, a.w);
          r2 = pkh(b.x, b.y); r3 = pkh(b.z, b.w);
        } else {
          r0 = pkh(a.x - h2f(a.x), a.y - h2f(a.y));
          r1 = pkh(a.z - h2f(a.z), a.w - h2f(a.w));
          r2 = pkh(b.x - h2f(b.x), b.y - h2f(b.y));
          r3 = pkh(b.z - h2f(b.z), b.w - h2f(b.w));
        }
        if (T == 0) { Bx0.u[0] = r0; Bx0.u[1] = r1; Bx0.u[2] = r2; Bx0.u[3] = r3; }
        else        { Bx1.u[0] = r0; Bx1.u[1] = r1; Bx1.u[2] = r2; Bx1.u[3] = r3; }
      }
      f4 macc0 = {0.f, 0.f, 0.f, 0.f}, macc1 = {0.f, 0.f, 0.f, 0.f};
      f4 lacc0 = {0.f, 0.f, 0.f, 0.f}, lacc1 = {0.f, 0.f, 0.f, 0.f};

      // chunk pipeline: this wave's 16 chunks {cpar, cpar+2, ...}, 1 ahead
      // (a-regs preloaded with chunk cpar by prologue / previous phase tail)
#pragma unroll 1
      for (int j = 0; j < 16; j += 2) {
        LOADF(b, cpar + 2 * (j + 1));
        COMPUTE(a, cpar + 2 * j);
        if (j + 2 < 16) LOADF(a, cpar + 2 * (j + 2));
        COMPUTE(b, cpar + 2 * (j + 1));
      }

      // partials: macc per lane; lsum complete per tok in lacc (any row reg)
      *(f4*)(redMp + ((wave * 2 + 0) * 64 + lane) * 16) = macc0;
      *(f4*)(redMp + ((wave * 2 + 1) * 64 + lane) * 16) = macc1;
      if (lane < 16) {
        redL[wave * 32 + lane] = lacc0[0];
        redL[wave * 32 + 16 + lane] = lacc1[0];
      }
      __syncthreads();
      // prefetch next phase's first chunk — L2 latency hides under finalize
      LOADF(a, cpar);
      // z table for the NEXT phase — overlaps the finalize serial window
      const float ttn = (mh == 0) ? (tt + 0.5f * dt) : ((float)(step + 1) * dt);
      ZFILL(ttn);
      if ((wave & 7) == 0) {  // waves 0 (tile0) and 8 (tile1) finalize
        const int T2 = wave >> 3;
        f4 m = {0.f, 0.f, 0.f, 0.f};
        float l2 = 0.f;
#pragma unroll
        for (int w = 0; w < 16; w++) {
          f4 o = *(const f4*)(redMp + ((w * 2 + T2) * 64 + lane) * 16);
          m += o;
          l2 += redL[w * 32 + T2 * 16 + q];
        }
        const float inv = 1.0f / fmaxf(l2, 1e-37f);
        const float inv1 = 1.0f / (1.0f - tt + 1e-10f);
        const float cf = (mh == 0) ? (0.5f * dt * inv1) : (dt * inv1);
        // lane owns (tok=q, d=g*4+j) of its tile: contiguous float4
        float4 xb = *(const float4*)(xT + (T2 * 16 + q) * 16 + g * 4);
        float4 xs = mh ? *(const float4*)(xM + (T2 * 16 + q) * 16 + g * 4) : xb;
        float4 xn;
        xn.x = fmaf(cf, m[0] * inv - xs.x, xb.x);
        xn.y = fmaf(cf, m[1] * inv - xs.y, xb.y);
        xn.z = fmaf(cf, m[2] * inv - xs.z, xb.z);
        xn.w = fmaf(cf, m[3] * inv - xs.w, xb.w);
        *(float4*)((mh ? xT : xM) + (T2 * 16 + q) * 16 + g * 4) = xn;
      }
      __syncthreads();
    }
  }

  // ---- outputs: x_final ----
  if (tid < 128)
    *(float4*)(out + tok0 * 16 + tid * 4) = *(const float4*)(xT + tid * 4);

  // ---- VQ argmin via bf16 MFMA (bit-identical to R10): dist = cc - 2 x.c ----
  union { u32 u[4]; s8v v; } Vx0, Vx1;
#pragma unroll
  for (int T = 0; T < 2; T++) {
    const float* xp = xT + (T * 16 + q) * 16 + (g & 1) * 8;
    float4 a = *(const float4*)(xp);
    float4 b = *(const float4*)(xp + 4);
    u32 h0 = cvtpk(a.x, a.y), h1 = cvtpk(a.z, a.w);
    u32 h2 = cvtpk(b.x, b.y), h3 = cvtpk(b.z, b.w);
    u32 r0, r1, r2, r3;
    if (g < 2) {
      r0 = h0; r1 = h1; r2 = h2; r3 = h3;
    } else {
      r0 = cvtpk(a.x - lof(h0), a.y - hif(h0));
      r1 = cvtpk(a.z - lof(h1), a.w - hif(h1));
      r2 = cvtpk(b.x - lof(h2), b.y - hif(h2));
      r3 = cvtpk(b.z - lof(h3), b.w - hif(h3));
    }
    if (T == 0) { Vx0.u[0] = r0; Vx0.u[1] = r1; Vx0.u[2] = r2; Vx0.u[3] = r3; }
    else        { Vx1.u[0] = r0; Vx1.u[1] = r1; Vx1.u[2] = r2; Vx1.u[3] = r3; }
  }
  float mv0 = 3.402823466e38f, mv1 = 3.402823466e38f;
  int mi0 = 0, mi1 = 0;
  s8v pAh0, pAl0, pAh1, pAl1;
  s8v qAh0, qAl0, qAh1, qAl1;
  float4 pC0, pC1, qC0, qC1;

#define VQLOAD(P, c) {                                                      \
    const char* _a = ws + WS_VQA + (size_t)(c) * 32768;                     \
    P##Ah0 = *(const s8v*)(_a + s2 * 1024 + lane * 16);                     \
    P##Al0 = *(const s8v*)(_a + 16384 + s2 * 1024 + lane * 16);             \
    P##Ah1 = *(const s8v*)(_a + (s2 + 1) * 1024 + lane * 16);               \
    P##Al1 = *(const s8v*)(_a + 16384 + (s2 + 1) * 1024 + lane * 16);       \
    P##C0 = *(const float4*)(CC2 + (c) * 256 + s2 * 16 + (lane >> 4) * 4);  \
    P##C1 = *(const float4*)(CC2 + (c) * 256 + (s2 + 1) * 16 + (lane >> 4) * 4); \
  }

#define VQMIN(MV, MI, DV, IDX) { float _d = (DV); if (_d < MV) { MV = _d; MI = (IDX); } }

#define VQTILE(P, VX, MV, MI, c) {                                          \
    const int _b0 = (c) * 256 + s2 * 16 + (lane >> 4) * 4;                  \
    const int _b1 = _b0 + 16;                                               \
    f4 _E0 = {P##C0.x, P##C0.y, P##C0.z, P##C0.w};                          \
    _E0 = __builtin_amdgcn_mfma_f32_16x16x32_bf16(P##Ah0, VX, _E0, 0, 0, 0);\
    _E0 = __builtin_amdgcn_mfma_f32_16x16x32_bf16(P##Al0, VX, _E0, 0, 0, 0);\
    f4 _E1 = {P##C1.x, P##C1.y, P##C1.z, P##C1.w};                          \
    _E1 = __builtin_amdgcn_mfma_f32_16x16x32_bf16(P##Ah1, VX, _E1, 0, 0, 0);\
    _E1 = __builtin_amdgcn_mfma_f32_16x16x32_bf16(P##Al1, VX, _E1, 0, 0, 0);\
    VQMIN(MV, MI, _E0[0], _b0 + 0); VQMIN(MV, MI, _E0[1], _b0 + 1);         \
    VQMIN(MV, MI, _E0[2], _b0 + 2); VQMIN(MV, MI, _E0[3], _b0 + 3);         \
    VQMIN(MV, MI, _E1[0], _b1 + 0); VQMIN(MV, MI, _E1[1], _b1 + 1);         \
    VQMIN(MV, MI, _E1[2], _b1 + 2); VQMIN(MV, MI, _E1[3], _b1 + 3);         \
  }

#define VQSTEP(P, c) { VQTILE(P, Vx0.v, mv0, mi0, c) VQTILE(P, Vx1.v, mv1, mi1, c) }

  VQLOAD(p, cpar);
#pragma unroll 1
  for (int i = 0; i < 16; i += 2) {
    VQLOAD(q, cpar + 2 * (i + 1));
    VQSTEP(p, cpar + 2 * i);
    if (i + 2 < 16) VQLOAD(p, cpar + 2 * (i + 2));
    VQSTEP(q, cpar + 2 * (i + 1));
  }
  // cross-lane argmin over the 4 lanes sharing tok = lane&15 (rows)
#pragma unroll
  for (int m = 16; m < 64; m <<= 1) {
    float ov0 = __shfl_xor(mv0, m, 64); int oi0 = __shfl_xor(mi0, m, 64);
    if (ov0 < mv0 || (ov0 == mv0 && oi0 < mi0)) { mv0 = ov0; mi0 = oi0; }
    float ov1 = __shfl_xor(mv1, m, 64); int oi1 = __shfl_xor(mi1, m, 64);
    if (ov1 < mv1 || (ov1 == mv1 && oi1 < mi1)) { mv1 = ov1; mi1 = oi1; }
  }
  if (lane < 16) {
    redV[wave * 32 + lane] = mv0; redI[wave * 32 + lane] = mi0;
    redV[wave * 32 + 16 + lane] = mv1; redI[wave * 32 + 16 + lane] = mi1;
  }
  __syncthreads();
  if (tid < 32) {
    float bv = redV[tid];
    int bi = redI[tid];
#pragma unroll
    for (int w = 1; w < 16; w++) {
      float ov = redV[w * 32 + tid];
      int oi = redI[w * 32 + tid];
      if (ov < bv || (ov == bv && oi < bi)) { bv = ov; bi = oi; }
    }
    out[NTOK * 16 + tok0 + tid] = (float)bi;
  }
}

extern "C" void kernel_launch(void* const* d_in, const int* in_sizes, int n_in,
                              void* d_out, int out_size, void* d_ws, size_t ws_size,
                              hipStream_t stream) {
  const float* x0 = (const float*)d_in[0];
  const float* cb = (const float*)d_in[1];
  const float* Wm = (const float*)d_in[2];
  const float* bm = (const float*)d_in[3];
  const float* tp = (const float*)d_in[4];
  const int* ns = (const int*)d_in[5];
  char* ws = (char*)d_ws;  // needs 1933312 B
  float* out = (float*)d_out;

  prep_kernel<<<512, 64, 0, stream>>>(cb, Wm, bm, tp, ws);
  flow_kernel<<<256, 1024, 0, stream>>>(x0, ws, cb, ns, out);
}

// Round 14
// 248.534 us; speedup vs baseline: 5.3622x; 1.2590x over previous
//
#include <hip/hip_runtime.h>

#define KS 1.8033688011112042f  // log2(e)/0.8
#define ZSH 8.0f                // constant exponent shift: E *= 2^-8 (cancels in mu)
#define NTOK 8192
#define VV 8192
#define CHB 26624               // f16 chunk: W 16K + C 8K + BB 1K + BT 1K
#define WS_CC2B 851968
#define WS_VQA  884736          // (-2C) bf16 hi/lo frags, 32 x 32768 -> ws 1933312 B

typedef float f4 __attribute__((ext_vector_type(4)));
typedef short s8v __attribute__((ext_vector_type(8)));
typedef _Float16 h8v __attribute__((ext_vector_type(8)));
typedef __fp16 fp16v2 __attribute__((ext_vector_type(2)));  // builtin's return type
typedef unsigned int u32;
#define AS1 __attribute__((address_space(1)))
#define AS3 __attribute__((address_space(3)))

// RNE float->bf16, bit-ops (prep + VQ path)
static __device__ __forceinline__ unsigned short f2bf(float f) {
  u32 u = __float_as_uint(f);
  return (unsigned short)((u + 0x7fffu + ((u >> 16) & 1u)) >> 16);
}
static __device__ __forceinline__ unsigned short f2h(float f) {  // RNE f32->f16
  _Float16 h = (_Float16)f;
  return __builtin_bit_cast(unsigned short, h);
}
// f16 pack via PLAIN CASTS (RNE; used on the cold x-packing path)
static __device__ __forceinline__ u32 pkh(float a, float b) {
  return (u32)f2h(a) | ((u32)f2h(b) << 16);
}
static __device__ __forceinline__ float h2f(float a) {  // RNE f16 of a, as f32
  return (float)(_Float16)a;
}
// official builtin packed RTZ f16 conversion (hot E-packing path; R12 proved
// the hand-asm variant was R11's NaN source — use the compiler-owned builtin)
static __device__ __forceinline__ u32 pkrtz_b(float a, float b) {
  fp16v2 r = __builtin_amdgcn_cvt_pkrtz(a, b);
  return __builtin_bit_cast(u32, r);
}
// bf16 pack for the VQ path (proven since R3)
static __device__ __forceinline__ u32 cvtpk(float a, float b) {
  u32 r;
  asm("v_cvt_pk_bf16_f32 %0, %1, %2" : "=v"(r) : "v"(a), "v"(b));
  return r;
}
static __device__ __forceinline__ float lof(u32 h) {  // low bf16 as f32
  return __uint_as_float(h << 16);
}
static __device__ __forceinline__ float hif(u32 h) {  // high bf16 as f32
  return __uint_as_float(h & 0xffff0000u);
}

// ws layout (f16 flow path): 32 chunks x 26624 B:
//   [0,16384)     Wf16: 16 subtiles x 64 lanes x 8 f16 (A of mfma1, W*KS, RNE)
//   [16384,24576) Cf16: 8 PAIRS x 64 lanes x 8 f16 (A of mfma2, K=32 pairing)
//   [24576,25600) BB fp32[256] (bm*KS - 8)   [25600,26624) BT fp32[256]
// CC2 fp32[8192] at WS_CC2B; VQA ((-2C) bf16 hi/lo, mfma1-A layout) at WS_VQA.
// Exponent shift -8 keeps E in f16 range (overflow needs a 13-sigma logit;
// R12 proved the clamp never fires -> removed).
__global__ __launch_bounds__(64) void prep_kernel(
    const float* __restrict__ cb, const float* __restrict__ Wm,
    const float* __restrict__ bm, const float* __restrict__ tp,
    char* __restrict__ ws) {
  const int ct = blockIdx.x;  // subtile 0..511 (16 codes)
  const int l = threadIdx.x;
  const int g = l >> 4, q = l & 15;
  const int c = ct >> 4, p = ct & 15;
  const int s = p >> 1, par = p & 1;
  char* chunk = ws + (size_t)c * CHB;
  {  // W fragment (A of mfma1): row=code=ct*16+q, k=g*8+j, d=k&15, f16 RNE
    const int code = ct * 16 + q;
    unsigned short wh[8];
#pragma unroll
    for (int j = 0; j < 8; j++) {
      int d = (g * 8 + j) & 15;
      wh[j] = f2h(Wm[d * VV + code] * KS);
    }
    uint4 hv;
    hv.x = (u32)wh[0] | ((u32)wh[1] << 16); hv.y = (u32)wh[2] | ((u32)wh[3] << 16);
    hv.z = (u32)wh[4] | ((u32)wh[5] << 16); hv.w = (u32)wh[6] | ((u32)wh[7] << 16);
    *(uint4*)(chunk + p * 1024 + l * 16) = hv;
  }
  {  // VQ A-fragment: (-2*C) bf16 hi/lo in mfma1-A layout (unchanged, proven)
    const int code = ct * 16 + q;
    unsigned short vh[8], vo[8];
#pragma unroll
    for (int j = 0; j < 8; j++) {
      int d = (g * 8 + j) & 15;
      float v = -2.0f * cb[code * 16 + d];
      unsigned short h = f2bf(v);
      vh[j] = h;
      vo[j] = f2bf(v - __uint_as_float((u32)h << 16));
    }
    uint4 hv, lv;
    hv.x = (u32)vh[0] | ((u32)vh[1] << 16); hv.y = (u32)vh[2] | ((u32)vh[3] << 16);
    hv.z = (u32)vh[4] | ((u32)vh[5] << 16); hv.w = (u32)vh[6] | ((u32)vh[7] << 16);
    lv.x = (u32)vo[0] | ((u32)vo[1] << 16); lv.y = (u32)vo[2] | ((u32)vo[3] << 16);
    lv.z = (u32)vo[4] | ((u32)vo[5] << 16); lv.w = (u32)vo[6] | ((u32)vo[7] << 16);
    char* vq = ws + WS_VQA + (size_t)c * 32768;
    *(uint4*)(vq + p * 1024 + l * 16) = hv;
    *(uint4*)(vq + 16384 + p * 1024 + l * 16) = lv;
  }
  {  // C pair-fragment (A of mfma2), f16 RNE: elems par*4+{0..3} of pair s
    unsigned short ch[4];
#pragma unroll
    for (int j = 0; j < 4; j++) {
      int code = ct * 16 + g * 4 + j;
      ch[j] = f2h(cb[code * 16 + q]);
    }
    uint2 hv = make_uint2((u32)ch[0] | ((u32)ch[1] << 16),
                          (u32)ch[2] | ((u32)ch[3] << 16));
    *(uint2*)(chunk + 16384 + s * 1024 + l * 16 + par * 8) = hv;
  }
  if (l < 16) {
    const int code = ct * 16 + l;
    *(float*)(chunk + 24576 + p * 64 + l * 4) = bm[code] * KS - ZSH;
    *(float*)(chunk + 25600 + p * 64 + l * 4) = tp[code] * KS;
    float ss = 0.f;
#pragma unroll
    for (int d = 0; d < 16; d++) { float v = cb[code * 16 + d]; ss = fmaf(v, v, ss); }
    *(float*)(ws + WS_CC2B + code * 4) = ss;
  }
}

// R14 = R13 with the compile fix (builtin pkrtz returns __fp16 vector; receive
// in matching typedef + bit_cast). TBODY VALU mass cut 28 -> 12 ops:
//  - fminf clamp REMOVED (R12 proved it runtime-dead: absmax bit-matched).
//  - E packed via __builtin_amdgcn_cvt_pkrtz (official builtin, 1 inst/pair;
//    R11's failure isolated to the hand-written asm variant, not the op).
//    RTZ bias cancels in the mu ratio; E has no hi/lo split.
// Structure identical to R12: zL table, direct L2->VGPR streaming, wave-
// private chunks, named double-buffered regs (rule #20), 2 barriers/phase,
// prefetch in finalize window, VQ argmin via bf16 MFMA (bit-identical to R10).
__global__ __launch_bounds__(1024, 4) void flow_kernel(
    const float* __restrict__ x0, const char* __restrict__ ws,
    const float* __restrict__ cb, const int* __restrict__ nsp,
    float* __restrict__ out) {
  __shared__ __align__(16) char smem[141312];
  char* biasL = smem;                       // [32 chunks][2048 B] BB|BT
  float* xT = (float*)(smem + 65536);       // [32][16] base state
  float* xM = (float*)(smem + 67584);       // [32][16] midpoint state
  char* redMp = smem + 69632;               // [16 waves][2 tiles][64] f4 (32 KB)
  float* redL = (float*)(smem + 102400);    // [16][32] lsum partials
  float* redV = (float*)(smem + 104448);    // [16][32] VQ min val
  int* redI = (int*)(smem + 106496);        // [16][32] VQ min idx
  float* zL = (float*)(smem + 108544);      // [32 chunks][256] z table (32 KB)
  const float* CC2 = (const float*)(ws + WS_CC2B);

  const int tid = threadIdx.x;
  const int lane = tid & 63, wave = tid >> 6;  // 16 waves
  const int s = wave & 7, cpar = wave >> 3;    // pair id, chunk parity
  const int s2 = s * 2;
  const int g = lane >> 4, q = lane & 15;
  const int tok0 = blockIdx.x * 32;

  if (tid < 128)
    *(float4*)(xT + tid * 4) = *(const float4*)(x0 + tok0 * 16 + tid * 4);
  // biases -> LDS once (wave-uniform dst base + lane*16: valid global_load_lds)
#pragma unroll
  for (int sw = 0; sw < 4; sw++) {
    const int c = sw * 8 + (tid >> 7);
    const int off = (tid & 127) * 16;
    __builtin_amdgcn_global_load_lds(
        (const AS1 u32*)(ws + (size_t)c * CHB + 24576 + off),
        (AS3 u32*)(biasL + c * 2048 + off), 16, 0, 0);
  }
  __syncthreads();

  const int n_steps = *nsp;
  const float dt = 1.0f / (float)(n_steps - 1);

  // ones A-fragment (f16 1.0 pairs) for the lsum MFMA
  union { u32 u[4]; h8v h; } ONESH;
  ONESH.u[0] = ONESH.u[1] = ONESH.u[2] = ONESH.u[3] = 0x3c003c00u;

  // named double-buffered fragment registers (NO arrays — rule #20)
  h8v aW0, aW1, aCf;
  h8v bW0, bW1, bCf;

// conflict-light ZFILL: lanes write 16-B-contiguous (2 passes of 128 floats)
#define ZFILL(TT) {                                                         \
    const int _c = tid >> 5;                                                \
    const int _t = tid & 31;                                                \
    const char* _bp = biasL + _c * 2048;                                    \
    float4 _b0 = *(const float4*)(_bp + _t * 16);                           \
    float4 _t0 = *(const float4*)(_bp + 1024 + _t * 16);                    \
    float4 _b1 = *(const float4*)(_bp + 512 + _t * 16);                     \
    float4 _t1 = *(const float4*)(_bp + 1536 + _t * 16);                    \
    float4 _za, _zb;                                                        \
    _za.x = fmaf(TT, _t0.x, _b0.x); _za.y = fmaf(TT, _t0.y, _b0.y);         \
    _za.z = fmaf(TT, _t0.z, _b0.z); _za.w = fmaf(TT, _t0.w, _b0.w);         \
    _zb.x = fmaf(TT, _t1.x, _b1.x); _zb.y = fmaf(TT, _t1.y, _b1.y);         \
    _zb.z = fmaf(TT, _t1.z, _b1.z); _zb.w = fmaf(TT, _t1.w, _b1.w);         \
    *(float4*)(zL + _c * 256 + _t * 4) = _za;                               \
    *(float4*)(zL + _c * 256 + 128 + _t * 4) = _zb;                         \
  }

#define LOADF(P, c) {                                                       \
    const char* _p = ws + (size_t)(c) * CHB;                                \
    P##W0 = *(const h8v*)(_p + s2 * 1024 + lane * 16);                      \
    P##W1 = *(const h8v*)(_p + (s2 + 1) * 1024 + lane * 16);                \
    P##Cf = *(const h8v*)(_p + 16384 + s * 1024 + lane * 16);               \
  }

#define TBODY(W0F, W1F, CFF, BX, MACC, LACC, Z0, Z1) {                      \
    f4 _D0 = {Z0.x, Z0.y, Z0.z, Z0.w};  /* bias (incl -8 shift) as C-in */  \
    _D0 = __builtin_amdgcn_mfma_f32_16x16x32_f16(W0F, BX, _D0, 0, 0, 0);    \
    f4 _D1 = {Z1.x, Z1.y, Z1.z, Z1.w};                                      \
    _D1 = __builtin_amdgcn_mfma_f32_16x16x32_f16(W1F, BX, _D1, 0, 0, 0);    \
    float _e0 = __builtin_amdgcn_exp2f(_D0[0]);                             \
    float _e1 = __builtin_amdgcn_exp2f(_D0[1]);                             \
    float _e2 = __builtin_amdgcn_exp2f(_D0[2]);                             \
    float _e3 = __builtin_amdgcn_exp2f(_D0[3]);                             \
    float _e4 = __builtin_amdgcn_exp2f(_D1[0]);                             \
    float _e5 = __builtin_amdgcn_exp2f(_D1[1]);                             \
    float _e6 = __builtin_amdgcn_exp2f(_D1[2]);                             \
    float _e7 = __builtin_amdgcn_exp2f(_D1[3]);                             \
    union { u32 u[4]; h8v h; } _Eh;                                         \
    _Eh.u[0] = pkrtz_b(_e0, _e1); _Eh.u[1] = pkrtz_b(_e2, _e3);             \
    _Eh.u[2] = pkrtz_b(_e4, _e5); _Eh.u[3] = pkrtz_b(_e6, _e7);             \
    MACC = __builtin_amdgcn_mfma_f32_16x16x32_f16(CFF, _Eh.h, MACC, 0, 0, 0); \
    LACC = __builtin_amdgcn_mfma_f32_16x16x32_f16(ONESH.h, _Eh.h, LACC, 0, 0, 0); \
  }

#define COMPUTE(P, c) {                                                     \
    const float* _zp = zL + (c) * 256 + s2 * 16 + g * 4;                    \
    float4 _z0 = *(const float4*)(_zp);                                     \
    float4 _z1 = *(const float4*)(_zp + 16);                                \
    TBODY(P##W0, P##W1, P##Cf, Bx0.h, macc0, lacc0, _z0, _z1);              \
    TBODY(P##W0, P##W1, P##Cf, Bx1.h, macc1, lacc1, _z0, _z1);              \
  }

  // prologue: z table for phase 0 (tt = 0) + first chunk prefetch
  ZFILL(0.0f);
  LOADF(a, cpar);
  __syncthreads();

  for (int step = 0; step < n_steps - 1; step++) {
#pragma unroll 1
    for (int mh = 0; mh < 2; mh++) {
      const float tt = (float)step * dt + (mh ? 0.5f * dt : 0.0f);
      const float* xsrc = mh ? xM : xT;
      // B-frags of mfma1: col=tok=q, k=g*8+j; k<16 -> xh[d=k] (f16 RNE),
      // k>=16 -> xl[d=k-16] (residual vs the same RNE). g covers d=(g&1)*8..+7.
      union { u32 u[4]; h8v h; } Bx0, Bx1;
#pragma unroll
      for (int T = 0; T < 2; T++) {
        const float* xp = xsrc + (T * 16 + q) * 16 + (g & 1) * 8;
        float4 a = *(const float4*)(xp);
        float4 b = *(const float4*)(xp + 4);
        u32 r0, r1, r2, r3;
        if (g < 2) {
          r0 = pkh(a.x, a.y); r1 = pkh(a.z, a.w);
          r2 = pkh(b.x, b.y); r3 = pkh(b.z, b.w);
        } else {
          r0 = pkh(a.x - h2f(a.x), a.y - h2f(a.y));
          r1 = pkh(a.z - h2f(a.z), a.w - h2f(a.w));
          r2 = pkh(b.x - h2f(b.x), b.y - h2f(b.y));
          r3 = pkh(b.z - h2f(b.z), b.w - h2f(b.w));
        }
        if (T == 0) { Bx0.u[0] = r0; Bx0.u[1] = r1; Bx0.u[2] = r2; Bx0.u[3] = r3; }
        else        { Bx1.u[0] = r0; Bx1.u[1] = r1; Bx1.u[2] = r2; Bx1.u[3] = r3; }
      }
      f4 macc0 = {0.f, 0.f, 0.f, 0.f}, macc1 = {0.f, 0.f, 0.f, 0.f};
      f4 lacc0 = {0.f, 0.f, 0.f, 0.f}, lacc1 = {0.f, 0.f, 0.f, 0.f};

      // chunk pipeline: this wave's 16 chunks {cpar, cpar+2, ...}, 1 ahead
      // (a-regs preloaded with chunk cpar by prologue / previous phase tail)
#pragma unroll 1
      for (int j = 0; j < 16; j += 2) {
        LOADF(b, cpar + 2 * (j + 1));
        COMPUTE(a, cpar + 2 * j);
        if (j + 2 < 16) LOADF(a, cpar + 2 * (j + 2));
        COMPUTE(b, cpar + 2 * (j + 1));
      }

      // partials: macc per lane; lsum complete per tok in lacc (any row reg)
      *(f4*)(redMp + ((wave * 2 + 0) * 64 + lane) * 16) = macc0;
      *(f4*)(redMp + ((wave * 2 + 1) * 64 + lane) * 16) = macc1;
      if (lane < 16) {
        redL[wave * 32 + lane] = lacc0[0];
        redL[wave * 32 + 16 + lane] = lacc1[0];
      }
      __syncthreads();
      // prefetch next phase's first chunk — L2 latency hides under finalize
      LOADF(a, cpar);
      // z table for the NEXT phase — overlaps the finalize serial window
      const float ttn = (mh == 0) ? (tt + 0.5f * dt) : ((float)(step + 1) * dt);
      ZFILL(ttn);
      if ((wave & 7) == 0) {  // waves 0 (tile0) and 8 (tile1) finalize
        const int T2 = wave >> 3;
        f4 m = {0.f, 0.f, 0.f, 0.f};
        float l2 = 0.f;
#pragma unroll
        for (int w = 0; w < 16; w++) {
          f4 o = *(const f4*)(redMp + ((w * 2 + T2) * 64 + lane) * 16);
          m += o;
          l2 += redL[w * 32 + T2 * 16 + q];
        }
        const float inv = 1.0f / fmaxf(l2, 1e-37f);
        const float inv1 = 1.0f / (1.0f - tt + 1e-10f);
        const float cf = (mh == 0) ? (0.5f * dt * inv1) : (dt * inv1);
        // lane owns (tok=q, d=g*4+j) of its tile: contiguous float4
        float4 xb = *(const float4*)(xT + (T2 * 16 + q) * 16 + g * 4);
        float4 xs = mh ? *(const float4*)(xM + (T2 * 16 + q) * 16 + g * 4) : xb;
        float4 xn;
        xn.x = fmaf(cf, m[0] * inv - xs.x, xb.x);
        xn.y = fmaf(cf, m[1] * inv - xs.y, xb.y);
        xn.z = fmaf(cf, m[2] * inv - xs.z, xb.z);
        xn.w = fmaf(cf, m[3] * inv - xs.w, xb.w);
        *(float4*)((mh ? xT : xM) + (T2 * 16 + q) * 16 + g * 4) = xn;
      }
      __syncthreads();
    }
  }

  // ---- outputs: x_final ----
  if (tid < 128)
    *(float4*)(out + tok0 * 16 + tid * 4) = *(const float4*)(xT + tid * 4);

  // ---- VQ argmin via bf16 MFMA (bit-identical to R10): dist = cc - 2 x.c ----
  union { u32 u[4]; s8v v; } Vx0, Vx1;
#pragma unroll
  for (int T = 0; T < 2; T++) {
    const float* xp = xT + (T * 16 + q) * 16 + (g & 1) * 8;
    float4 a = *(const float4*)(xp);
    float4 b = *(const float4*)(xp + 4);
    u32 h0 = cvtpk(a.x, a.y), h1 = cvtpk(a.z, a.w);
    u32 h2 = cvtpk(b.x, b.y), h3 = cvtpk(b.z, b.w);
    u32 r0, r1, r2, r3;
    if (g < 2) {
      r0 = h0; r1 = h1; r2 = h2; r3 = h3;
    } else {
      r0 = cvtpk(a.x - lof(h0), a.y - hif(h0));
      r1 = cvtpk(a.z - lof(h1), a.w - hif(h1));
      r2 = cvtpk(b.x - lof(h2), b.y - hif(h2));
      r3 = cvtpk(b.z - lof(h3), b.w - hif(h3));
    }
    if (T == 0) { Vx0.u[0] = r0; Vx0.u[1] = r1; Vx0.u[2] = r2; Vx0.u[3] = r3; }
    else        { Vx1.u[0] = r0; Vx1.u[1] = r1; Vx1.u[2] = r2; Vx1.u[3] = r3; }
  }
  float mv0 = 3.402823466e38f, mv1 = 3.402823466e38f;
  int mi0 = 0, mi1 = 0;
  s8v pAh0, pAl0, pAh1, pAl1;
  s8v qAh0, qAl0, qAh1, qAl1;
  float4 pC0, pC1, qC0, qC1;

#define VQLOAD(P, c) {                                                      \
    const char* _a = ws + WS_VQA + (size_t)(c) * 32768;                     \
    P##Ah0 = *(const s8v*)(_a + s2 * 1024 + lane * 16);                     \
    P##Al0 = *(const s8v*)(_a + 16384 + s2 * 1024 + lane * 16);             \
    P##Ah1 = *(const s8v*)(_a + (s2 + 1) * 1024 + lane * 16);               \
    P##Al1 = *(const s8v*)(_a + 16384 + (s2 + 1) * 1024 + lane * 16);       \
    P##C0 = *(const float4*)(CC2 + (c) * 256 + s2 * 16 + (lane >> 4) * 4);  \
    P##C1 = *(const float4*)(CC2 + (c) * 256 + (s2 + 1) * 16 + (lane >> 4) * 4); \
  }

#define VQMIN(MV, MI, DV, IDX) { float _d = (DV); if (_d < MV) { MV = _d; MI = (IDX); } }

#define VQTILE(P, VX, MV, MI, c) {                                          \
    const int _b0 = (c) * 256 + s2 * 16 + (lane >> 4) * 4;                  \
    const int _b1 = _b0 + 16;                                               \
    f4 _E0 = {P##C0.x, P##C0.y, P##C0.z, P##C0.w};                          \
    _E0 = __builtin_amdgcn_mfma_f32_16x16x32_bf16(P##Ah0, VX, _E0, 0, 0, 0);\
    _E0 = __builtin_amdgcn_mfma_f32_16x16x32_bf16(P##Al0, VX, _E0, 0, 0, 0);\
    f4 _E1 = {P##C1.x, P##C1.y, P##C1.z, P##C1.w};                          \
    _E1 = __builtin_amdgcn_mfma_f32_16x16x32_bf16(P##Ah1, VX, _E1, 0, 0, 0);\
    _E1 = __builtin_amdgcn_mfma_f32_16x16x32_bf16(P##Al1, VX, _E1, 0, 0, 0);\
    VQMIN(MV, MI, _E0[0], _b0 + 0); VQMIN(MV, MI, _E0[1], _b0 + 1);         \
    VQMIN(MV, MI, _E0[2], _b0 + 2); VQMIN(MV, MI, _E0[3], _b0 + 3);         \
    VQMIN(MV, MI, _E1[0], _b1 + 0); VQMIN(MV, MI, _E1[1], _b1 + 1);         \
    VQMIN(MV, MI, _E1[2], _b1 + 2); VQMIN(MV, MI, _E1[3], _b1 + 3);         \
  }

#define VQSTEP(P, c) { VQTILE(P, Vx0.v, mv0, mi0, c) VQTILE(P, Vx1.v, mv1, mi1, c) }

  VQLOAD(p, cpar);
#pragma unroll 1
  for (int i = 0; i < 16; i += 2) {
    VQLOAD(q, cpar + 2 * (i + 1));
    VQSTEP(p, cpar + 2 * i);
    if (i + 2 < 16) VQLOAD(p, cpar + 2 * (i + 2));
    VQSTEP(q, cpar + 2 * (i + 1));
  }
  // cross-lane argmin over the 4 lanes sharing tok = lane&15 (rows)
#pragma unroll
  for (int m = 16; m < 64; m <<= 1) {
    float ov0 = __shfl_xor(mv0, m, 64); int oi0 = __shfl_xor(mi0, m, 64);
    if (ov0 < mv0 || (ov0 == mv0 && oi0 < mi0)) { mv0 = ov0; mi0 = oi0; }
    float ov1 = __shfl_xor(mv1, m, 64); int oi1 = __shfl_xor(mi1, m, 64);
    if (ov1 < mv1 || (ov1 == mv1 && oi1 < mi1)) { mv1 = ov1; mi1 = oi1; }
  }
  if (lane < 16) {
    redV[wave * 32 + lane] = mv0; redI[wave * 32 + lane] = mi0;
    redV[wave * 32 + 16 + lane] = mv1; redI[wave * 32 + 16 + lane] = mi1;
  }
  __syncthreads();
  if (tid < 32) {
    float bv = redV[tid];
    int bi = redI[tid];
#pragma unroll
    for (int w = 1; w < 16; w++) {
      float ov = redV[w * 32 + tid];
      int oi = redI[w * 32 + tid];
      if (ov < bv || (ov == bv && oi < bi)) { bv = ov; bi = oi; }
    }
    out[NTOK * 16 + tok0 + tid] = (float)bi;
  }
}

extern "C" void kernel_launch(void* const* d_in, const int* in_sizes, int n_in,
                              void* d_out, int out_size, void* d_ws, size_t ws_size,
                              hipStream_t stream) {
  const float* x0 = (const float*)d_in[0];
  const float* cb = (const float*)d_in[1];
  const float* Wm = (const float*)d_in[2];
  const float* bm = (const float*)d_in[3];
  const float* tp = (const float*)d_in[4];
  const int* ns = (const int*)d_in[5];
  char* ws = (char*)d_ws;  // needs 1933312 B
  float* out = (float*)d_out;

  prep_kernel<<<512, 64, 0, stream>>>(cb, Wm, bm, tp, ws);
  flow_kernel<<<256, 1024, 0, stream>>>(x0, ws, cb, ns, out);
}